// Round 1
// baseline (3006.259 us; speedup 1.0000x reference)
//
#include <hip/hip_runtime.h>

// Problem constants
#define NSP   25600   // 25*32*32 spatial elems per (b, channel)
#define HWC   1024    // 32*32
#define TOKENS 102400 // 4*25*1024

// Attention table:
// att 0 (sf): ch_off=0,  M=1024, KC=25   (K=800)
// att 1 (af): ch_off=32, M=160,  KC=160  (K=5120)
// att 2 (sa): ch_off=64, M=160,  KC=320  (K=10240)
// All K-axes are re-permuted into chunks of 32 contiguous floats (w fastest).
// This is legal: fold K-order only needs to be consistent between q/k/v/unfold.

__device__ __forceinline__ int row_base(int att, int b, int m) {
    if (att == 0) { int cc = m >> 5, h = m & 31;   return (b*128 + cc)*NSP + h*32; }
    else if (att == 1) { int cc = m / 5, u = m - cc*5; return (b*128 + 32 + cc)*NSP + u*5120; }
    else { int h = m / 5, u = m - h*5;            return (b*128 + 64)*NSP + u*5120 + h*32; }
}

__device__ __forceinline__ int chunk_off(int att, int kc) {
    if (att == 0) return kc * 1024;                 // kc = u*5+v
    else if (att == 1) return kc * 32;              // kc = v*32+h
    else { int cc = kc / 5, v = kc - cc*5; return cc*NSP + v*1024; } // kc = cc*5+v
}

// ---------------- K1: token GEMMs  q = x_hf @ W_in, kv = x_lf @ W_kv -------
__global__ __launch_bounds__(256) void k_tokens(
        const float* __restrict__ x_hf, const float* __restrict__ x_lf,
        const float* __restrict__ W_in, const float* __restrict__ W_kv,
        float* __restrict__ q, float* __restrict__ kv) {
    // grid (100, 4, 2)
    int st = blockIdx.x, b = blockIdx.y, which = blockIdx.z;
    const float* x  = which ? x_lf : x_hf;
    const float* Wt = which ? W_kv : W_in;
    float* out = which ? kv : q;
    __shared__ float Wl[64 * 128];
    for (int i = threadIdx.x; i < 64 * 128; i += 256) Wl[i] = Wt[i];
    __syncthreads();
    int s = st * 256 + threadIdx.x;
    float acc[128];
#pragma unroll
    for (int d = 0; d < 128; ++d) acc[d] = 0.f;
    for (int c = 0; c < 64; ++c) {
        float xv = x[(b * 64 + c) * NSP + s];
#pragma unroll
        for (int d = 0; d < 128; ++d) acc[d] += xv * Wl[c * 128 + d];
    }
    for (int d = 0; d < 128; ++d) out[(b * 128 + d) * NSP + s] = acc[d];
}

// ---------------- K2: row L2 norms ----------------------------------------
__global__ __launch_bounds__(256) void k_norms(
        const float* __restrict__ src, float* __restrict__ dst,
        int att, int M, int KC) {
    // grid (M, 4)
    int m = blockIdx.x, b = blockIdx.y;
    int base = row_base(att, b, m);
    float s = 0.f;
    int K = KC * 32;
    for (int k = threadIdx.x; k < K; k += 256) {
        float v = src[base + chunk_off(att, k >> 5) + (k & 31)];
        s += v * v;
    }
    __shared__ float red[256];
    red[threadIdx.x] = s; __syncthreads();
    for (int w = 128; w >= 1; w >>= 1) {
        if (threadIdx.x < w) red[threadIdx.x] += red[threadIdx.x + w];
        __syncthreads();
    }
    if (threadIdx.x == 0) dst[b * M + m] = fmaxf(sqrtf(red[0]), 1e-12f);
}

// ---------------- K3: S = (q/|q|) @ (k/|k|)^T  (causal tiles only) --------
__global__ __launch_bounds__(256) void k_sgemm(
        const float* __restrict__ q, const float* __restrict__ kv,
        const float* __restrict__ nq, const float* __restrict__ nk,
        float* __restrict__ S, int att, int M, int KC) {
    // grid (M/32, M/32, 4), block (16,16)
    if (blockIdx.y > blockIdx.x) return;   // fully above diagonal
    int mt = blockIdx.x * 32, nt = blockIdx.y * 32, b = blockIdx.z;
    __shared__ float Qa[32][33], Ka[32][33];
    float acc[2][2] = {};
    int tx = threadIdx.x, ty = threadIdx.y;
    int tid = ty * 16 + tx, lr = tid >> 5, lk = tid & 31;
    for (int kc = 0; kc < KC; ++kc) {
        int co = chunk_off(att, kc);
#pragma unroll
        for (int r = 0; r < 4; ++r) {
            int row = lr + r * 8;
            Qa[row][lk] = q [row_base(att, b, mt + row) + co + lk];
            Ka[row][lk] = kv[row_base(att, b, nt + row) + co + lk];
        }
        __syncthreads();
#pragma unroll
        for (int kk = 0; kk < 32; ++kk) {
            float a0 = Qa[ty][kk], a1 = Qa[ty + 16][kk];
            float b0 = Ka[tx][kk], b1 = Ka[tx + 16][kk];
            acc[0][0] += a0 * b0; acc[0][1] += a0 * b1;
            acc[1][0] += a1 * b0; acc[1][1] += a1 * b1;
        }
        __syncthreads();
    }
#pragma unroll
    for (int i = 0; i < 2; ++i)
#pragma unroll
        for (int j = 0; j < 2; ++j) {
            int m = mt + ty + i * 16, n = nt + tx + j * 16;
            float v = (n <= m) ? acc[i][j] / (nq[b * M + m] * nk[b * M + n]) : 0.f;
            S[((long)b * M + m) * M + n] = v;
        }
}

// ---------------- K4: causal softmax, zero-fill n>m -----------------------
__global__ __launch_bounds__(256) void k_softmax(float* __restrict__ S, int M) {
    // grid (M, 4)
    int m = blockIdx.x, b = blockIdx.y;
    float* row = S + ((long)b * M + m) * M;
    int len = m + 1;
    __shared__ float red[256];
    float mx = -1e30f;
    for (int i = threadIdx.x; i < len; i += 256) mx = fmaxf(mx, row[i]);
    red[threadIdx.x] = mx; __syncthreads();
    for (int w = 128; w >= 1; w >>= 1) {
        if (threadIdx.x < w) red[threadIdx.x] = fmaxf(red[threadIdx.x], red[threadIdx.x + w]);
        __syncthreads();
    }
    mx = red[0]; __syncthreads();
    float sum = 0.f;
    for (int i = threadIdx.x; i < len; i += 256) {
        float e = expf(row[i] - mx); row[i] = e; sum += e;
    }
    red[threadIdx.x] = sum; __syncthreads();
    for (int w = 128; w >= 1; w >>= 1) {
        if (threadIdx.x < w) red[threadIdx.x] += red[threadIdx.x + w];
        __syncthreads();
    }
    float inv = 1.f / red[0];
    for (int i = threadIdx.x; i < len; i += 256) row[i] *= inv;
    for (int i = len + threadIdx.x; i < M; i += 256) row[i] = 0.f;
}

// ---------------- K5: O = P @ V, unfold + residual into cat ---------------
__global__ __launch_bounds__(256) void k_ogemm(
        const float* __restrict__ P, const float* __restrict__ kv,
        float* __restrict__ cat, int att, int M, int KC) {
    // grid (M/32, KC, 4), block (16,16)
    int mt = blockIdx.x * 32, kc = blockIdx.y, b = blockIdx.z;
    int co = chunk_off(att, kc);
    __shared__ float Pa[32][33], Va[32][33];
    float acc[2][2] = {};
    int tx = threadIdx.x, ty = threadIdx.y;
    int tid = ty * 16 + tx, lr = tid >> 5, lk = tid & 31;
    int nmax = mt + 32; if (nmax > M) nmax = M;
    for (int nt = 0; nt < nmax; nt += 32) {
#pragma unroll
        for (int r = 0; r < 4; ++r) {
            int row = lr + r * 8;
            Pa[row][lk] = P[((long)b * M + mt + row) * M + nt + lk];
            Va[row][lk] = kv[row_base(att, b, nt + row) + co + lk];
        }
        __syncthreads();
#pragma unroll
        for (int kk = 0; kk < 32; ++kk) {
            float a0 = Pa[ty][kk], a1 = Pa[ty + 16][kk];
            float b0 = Va[kk][tx], b1 = Va[kk][tx + 16];
            acc[0][0] += a0 * b0; acc[0][1] += a0 * b1;
            acc[1][0] += a1 * b0; acc[1][1] += a1 * b1;
        }
        __syncthreads();
    }
#pragma unroll
    for (int i = 0; i < 2; ++i)
#pragma unroll
        for (int j = 0; j < 2; ++j) {
            int m = mt + ty + i * 16, k = tx + j * 16;
            int adr = row_base(att, b, m) + co + k;
            cat[adr] = acc[i][j] + kv[adr];   // residual: + tv (kv part)
        }
}

// ---------------- K6: transpose cat (b,d,s) -> ct (token, d) --------------
__global__ __launch_bounds__(256) void k_transpose(
        const float* __restrict__ cat, float* __restrict__ ct) {
    // grid (32, 4, 100), block (32, 8)
    __shared__ float t[32][33];
    int hwt = blockIdx.x * 32, dt = blockIdx.y * 32, bn = blockIdx.z;
    int b = bn / 25, uv = bn - b * 25;
    const float* src = cat + (long)b * 128 * NSP + uv * HWC;
    for (int r = threadIdx.y; r < 32; r += 8)
        t[r][threadIdx.x] = src[(dt + r) * NSP + hwt + threadIdx.x];
    __syncthreads();
    float* dst = ct + (long)bn * HWC * 128;
    for (int r = threadIdx.y; r < 32; r += 8)
        dst[(hwt + r) * 128 + dt + threadIdx.x] = t[threadIdx.x][r];
}

// ---------------- K7: LayerNorm stats -------------------------------------
__global__ __launch_bounds__(256) void k_lnstats(
        const float* __restrict__ ct, float* __restrict__ mu, float* __restrict__ rstd) {
    // grid (25600), 4 waves/block, one token per wave
    int t = blockIdx.x * 4 + (threadIdx.x >> 6);
    int lane = threadIdx.x & 63;
    const float* row = ct + (long)t * 128;
    float v0 = row[lane], v1 = row[lane + 64];
    float s = v0 + v1, s2 = v0 * v0 + v1 * v1;
    for (int o = 32; o >= 1; o >>= 1) { s += __shfl_down(s, o); s2 += __shfl_down(s2, o); }
    if (lane == 0) {
        float m = s * (1.f / 128.f);
        float var = s2 * (1.f / 128.f) - m * m;
        mu[t] = m; rstd[t] = rsqrtf(var + 1e-5f);
    }
}

// ---------------- K8: h1 = relu(LN(ct) @ W1) ------------------------------
__global__ __launch_bounds__(256) void k_mlp1(
        const float* __restrict__ ct, const float* __restrict__ mu,
        const float* __restrict__ rstd, const float* __restrict__ g,
        const float* __restrict__ be, const float* __restrict__ W1,
        float* __restrict__ h1) {
    // grid (3200, 4), block (16,16)
    int tt = blockIdx.x * 32, nt = blockIdx.y * 32;
    __shared__ float Aa[32][33], Bb[32][33];
    int tx = threadIdx.x, ty = threadIdx.y;
    int tid = ty * 16 + tx, lr = tid >> 5, lk = tid & 31;
    float acc[2][2] = {};
    for (int kc = 0; kc < 128; kc += 32) {
#pragma unroll
        for (int r = 0; r < 4; ++r) {
            int row = lr + r * 8;
            int t = tt + row;
            float x = ct[(long)t * 128 + kc + lk];
            Aa[row][lk] = (x - mu[t]) * rstd[t] * g[kc + lk] + be[kc + lk];
            Bb[row][lk] = W1[(kc + row) * 128 + nt + lk];
        }
        __syncthreads();
#pragma unroll
        for (int kk = 0; kk < 32; ++kk) {
            float a0 = Aa[ty][kk], a1 = Aa[ty + 16][kk];
            float b0 = Bb[kk][tx], b1 = Bb[kk][tx + 16];
            acc[0][0] += a0 * b0; acc[0][1] += a0 * b1;
            acc[1][0] += a1 * b0; acc[1][1] += a1 * b1;
        }
        __syncthreads();
    }
#pragma unroll
    for (int i = 0; i < 2; ++i)
#pragma unroll
        for (int j = 0; j < 2; ++j) {
            int t = tt + ty + i * 16, n = nt + tx + j * 16;
            h1[(long)t * 128 + n] = fmaxf(acc[i][j], 0.f);
        }
}

// ---------------- K9: m2 = h1 @ W2 + ct -----------------------------------
__global__ __launch_bounds__(256) void k_mlp2(
        const float* __restrict__ h1, const float* __restrict__ ct,
        const float* __restrict__ W2, float* __restrict__ m2) {
    int tt = blockIdx.x * 32, nt = blockIdx.y * 32;
    __shared__ float Aa[32][33], Bb[32][33];
    int tx = threadIdx.x, ty = threadIdx.y;
    int tid = ty * 16 + tx, lr = tid >> 5, lk = tid & 31;
    float acc[2][2] = {};
    for (int kc = 0; kc < 128; kc += 32) {
#pragma unroll
        for (int r = 0; r < 4; ++r) {
            int row = lr + r * 8;
            Aa[row][lk] = h1[(long)(tt + row) * 128 + kc + lk];
            Bb[row][lk] = W2[(kc + row) * 128 + nt + lk];
        }
        __syncthreads();
#pragma unroll
        for (int kk = 0; kk < 32; ++kk) {
            float a0 = Aa[ty][kk], a1 = Aa[ty + 16][kk];
            float b0 = Bb[kk][tx], b1 = Bb[kk][tx + 16];
            acc[0][0] += a0 * b0; acc[0][1] += a0 * b1;
            acc[1][0] += a1 * b0; acc[1][1] += a1 * b1;
        }
        __syncthreads();
    }
#pragma unroll
    for (int i = 0; i < 2; ++i)
#pragma unroll
        for (int j = 0; j < 2; ++j) {
            int t = tt + ty + i * 16, n = nt + tx + j * 16;
            m2[(long)t * 128 + n] = acc[i][j] + ct[(long)t * 128 + n];
        }
}

// ---------------- K10: out = m2 @ W_out, scatter to (b,64,25,32,32) -------
__global__ __launch_bounds__(256) void k_out(
        const float* __restrict__ m2, const float* __restrict__ Wo,
        float* __restrict__ out) {
    // grid (3200, 2), block (16,16); tokens along tx for coalesced stores
    int tt = blockIdx.x * 32, ot = blockIdx.y * 32;
    __shared__ float Aa[32][33], Bb[32][33];
    int tx = threadIdx.x, ty = threadIdx.y;
    int tid = ty * 16 + tx, lr = tid >> 5, lk = tid & 31;
    float acc[2][2] = {};
    for (int kc = 0; kc < 128; kc += 32) {
#pragma unroll
        for (int r = 0; r < 4; ++r) {
            int row = lr + r * 8;
            Aa[row][lk] = m2[(long)(tt + row) * 128 + kc + lk];
            Bb[row][lk] = Wo[(kc + row) * 64 + ot + lk];
        }
        __syncthreads();
#pragma unroll
        for (int kk = 0; kk < 32; ++kk) {
            float a0 = Aa[tx][kk], a1 = Aa[tx + 16][kk];  // token along tx
            float b0 = Bb[kk][ty], b1 = Bb[kk][ty + 16];  // o along ty
            acc[0][0] += a0 * b0; acc[0][1] += a0 * b1;
            acc[1][0] += a1 * b0; acc[1][1] += a1 * b1;
        }
        __syncthreads();
    }
#pragma unroll
    for (int i = 0; i < 2; ++i)
#pragma unroll
        for (int j = 0; j < 2; ++j) {
            int t = tt + tx + i * 16, o = ot + ty + j * 16;
            int bn = t >> 10, hw = t & 1023;
            int b = bn / 25, uv = bn - b * 25;
            out[((b * 64 + o) * 25 + uv) * 1024 + hw] = acc[i][j];
        }
}

// ---------------- launch ---------------------------------------------------
extern "C" void kernel_launch(void* const* d_in, const int* in_sizes, int n_in,
                              void* d_out, int out_size, void* d_ws, size_t ws_size,
                              hipStream_t stream) {
    const float* x_lf = (const float*)d_in[0];
    const float* x_hf = (const float*)d_in[1];
    const float* W_in = (const float*)d_in[2];
    const float* W_kv = (const float*)d_in[3];
    const float* ln_g = (const float*)d_in[4];
    const float* ln_b = (const float*)d_in[5];
    const float* W_m1 = (const float*)d_in[6];
    const float* W_m2 = (const float*)d_in[7];
    const float* W_ot = (const float*)d_in[8];
    float* out = (float*)d_out;

    float* ws  = (float*)d_ws;
    float* q    = ws;                    // 13,107,200
    float* kv   = ws + 13107200;         // 13,107,200
    float* cat  = ws + 26214400;         // 13,107,200
    float* S    = ws + 39321600;         // 4,194,304
    float* nq   = ws + 43515904;         // 4096
    float* nk   = nq + 4096;             // 4096
    float* mu   = nk + 4096;             // 102400
    float* rstd = mu + 102400;           // 102400
    float* ct   = q;                     // reuse: q dead after attention
    float* h1   = kv;                    // reuse: kv dead after attention
    float* m2   = cat;                   // reuse: cat dead after transpose

    // 1. token GEMMs
    k_tokens<<<dim3(100, 4, 2), 256, 0, stream>>>(x_hf, x_lf, W_in, W_kv, q, kv);

    // 2. three attentions
    const int Ms[3]  = {1024, 160, 160};
    const int KCs[3] = {25, 160, 320};
    for (int att = 0; att < 3; ++att) {
        int M = Ms[att], KC = KCs[att], MT = M / 32;
        k_norms<<<dim3(M, 4), 256, 0, stream>>>(q,  nq, att, M, KC);
        k_norms<<<dim3(M, 4), 256, 0, stream>>>(kv, nk, att, M, KC);
        k_sgemm<<<dim3(MT, MT, 4), dim3(16, 16), 0, stream>>>(q, kv, nq, nk, S, att, M, KC);
        k_softmax<<<dim3(M, 4), 256, 0, stream>>>(S, M);
        k_ogemm<<<dim3(MT, KC, 4), dim3(16, 16), 0, stream>>>(S, kv, cat, att, M, KC);
    }

    // 3. transpose to token-major
    k_transpose<<<dim3(32, 4, 100), dim3(32, 8), 0, stream>>>(cat, ct);

    // 4. LN + MLP + out projection
    k_lnstats<<<dim3(25600), 256, 0, stream>>>(ct, mu, rstd);
    k_mlp1<<<dim3(3200, 4), dim3(16, 16), 0, stream>>>(ct, mu, rstd, ln_g, ln_b, W_m1, h1);
    k_mlp2<<<dim3(3200, 4), dim3(16, 16), 0, stream>>>(h1, ct, W_m2, m2);
    k_out <<<dim3(3200, 2), dim3(16, 16), 0, stream>>>(m2, W_ot, out);
}

// Round 2
// 1382.449 us; speedup vs baseline: 2.1746x; 2.1746x over previous
//
#include <hip/hip_runtime.h>

// Problem constants
#define NSP   25600   // 25*32*32 spatial elems per (b, channel)
#define HWC   1024    // 32*32

// Attention table:
// att 0 (sf): ch_off=0,  M=1024, KC=25   (K=800)
// att 1 (af): ch_off=32, M=160,  KC=160  (K=5120)
// att 2 (sa): ch_off=64, M=160,  KC=320  (K=10240)
// K-axes re-permuted into chunks of 32 contiguous floats (legal: fold K-order
// only needs to be consistent between q/k/v/unfold).

__device__ __forceinline__ int row_base(int att, int b, int m) {
    if (att == 0) { int cc = m >> 5, h = m & 31;   return (b*128 + cc)*NSP + h*32; }
    else if (att == 1) { int cc = m / 5, u = m - cc*5; return (b*128 + 32 + cc)*NSP + u*5120; }
    else { int h = m / 5, u = m - h*5;            return (b*128 + 64)*NSP + u*5120 + h*32; }
}

__device__ __forceinline__ int chunk_off(int att, int kc) {
    if (att == 0) return kc * 1024;                 // kc = u*5+v
    else if (att == 1) return kc * 32;              // kc = v*32+h
    else { int cc = kc / 5, v = kc - cc*5; return cc*NSP + v*1024; } // kc = cc*5+v
}

// ---------------- K1: token GEMMs  q = x_hf @ W_in, kv = x_lf @ W_kv -------
__global__ __launch_bounds__(256) void k_tokens(
        const float* __restrict__ x_hf, const float* __restrict__ x_lf,
        const float* __restrict__ W_in, const float* __restrict__ W_kv,
        float* __restrict__ q, float* __restrict__ kv) {
    // grid (100, 4, 2)
    int st = blockIdx.x, b = blockIdx.y, which = blockIdx.z;
    const float* x  = which ? x_lf : x_hf;
    const float* Wt = which ? W_kv : W_in;
    float* out = which ? kv : q;
    __shared__ float Wl[64 * 128];
    for (int i = threadIdx.x; i < 64 * 128; i += 256) Wl[i] = Wt[i];
    __syncthreads();
    int s = st * 256 + threadIdx.x;
    float acc[128];
#pragma unroll
    for (int d = 0; d < 128; ++d) acc[d] = 0.f;
    for (int c = 0; c < 64; ++c) {
        float xv = x[(b * 64 + c) * NSP + s];
#pragma unroll
        for (int d = 0; d < 128; ++d) acc[d] += xv * Wl[c * 128 + d];
    }
    for (int d = 0; d < 128; ++d) out[(b * 128 + d) * NSP + s] = acc[d];
}

// ---------------- K2: row L2 norms ----------------------------------------
__global__ __launch_bounds__(256) void k_norms(
        const float* __restrict__ src, float* __restrict__ dst,
        int att, int M, int KC) {
    // grid (M, 4)
    int m = blockIdx.x, b = blockIdx.y;
    int base = row_base(att, b, m);
    float s = 0.f;
    int K = KC * 32;
    for (int k = threadIdx.x; k < K; k += 256) {
        float v = src[base + chunk_off(att, k >> 5) + (k & 31)];
        s += v * v;
    }
    __shared__ float red[256];
    red[threadIdx.x] = s; __syncthreads();
    for (int w = 128; w >= 1; w >>= 1) {
        if (threadIdx.x < w) red[threadIdx.x] += red[threadIdx.x + w];
        __syncthreads();
    }
    if (threadIdx.x == 0) dst[b * M + m] = fmaxf(sqrtf(red[0]), 1e-12f);
}

// ---------------- K3a: fused S-GEMM (att0 only: plenty of tiles) ----------
__global__ __launch_bounds__(256) void k_sgemm(
        const float* __restrict__ q, const float* __restrict__ kv,
        const float* __restrict__ nq, const float* __restrict__ nk,
        float* __restrict__ S, int att, int M, int KC) {
    // grid (M/32, M/32, 4), block (16,16)
    if (blockIdx.y > blockIdx.x) return;   // fully above diagonal
    int mt = blockIdx.x * 32, nt = blockIdx.y * 32, b = blockIdx.z;
    __shared__ float Qa[32][33], Ka[32][33];
    float acc[2][2] = {};
    int tx = threadIdx.x, ty = threadIdx.y;
    int tid = ty * 16 + tx, lr = tid >> 5, lk = tid & 31;
    for (int kc = 0; kc < KC; ++kc) {
        int co = chunk_off(att, kc);
#pragma unroll
        for (int r = 0; r < 4; ++r) {
            int row = lr + r * 8;
            Qa[row][lk] = q [row_base(att, b, mt + row) + co + lk];
            Ka[row][lk] = kv[row_base(att, b, nt + row) + co + lk];
        }
        __syncthreads();
#pragma unroll
        for (int kk = 0; kk < 32; ++kk) {
            float a0 = Qa[ty][kk], a1 = Qa[ty + 16][kk];
            float b0 = Ka[tx][kk], b1 = Ka[tx + 16][kk];
            acc[0][0] += a0 * b0; acc[0][1] += a0 * b1;
            acc[1][0] += a1 * b0; acc[1][1] += a1 * b1;
        }
        __syncthreads();
    }
#pragma unroll
    for (int i = 0; i < 2; ++i)
#pragma unroll
        for (int j = 0; j < 2; ++j) {
            int m = mt + ty + i * 16, n = nt + tx + j * 16;
            float v = (n <= m) ? acc[i][j] / (nq[b * M + m] * nk[b * M + n]) : 0.f;
            S[((long)b * M + m) * M + n] = v;
        }
}

// ---------------- K3b: split-K S-GEMM (att1/att2: few tiles, huge K) ------
__global__ __launch_bounds__(256) void k_sgemm_split(
        const float* __restrict__ q, const float* __restrict__ kv,
        float* __restrict__ Spart, int att, int M, int KC,
        int CPS, int nsplit, int ntiles) {
    // grid (ntiles, nsplit, 4), block (16,16); causal lower-triangle tiles
    int t = blockIdx.x, split = blockIdx.y, b = blockIdx.z;
    int i = 0;
    while (t >= (i + 1) * (i + 2) / 2) ++i;
    int j = t - i * (i + 1) / 2;
    int mt = i * 32, nt = j * 32;
    __shared__ float Qa[32][33], Ka[32][33];
    float acc[2][2] = {};
    int tx = threadIdx.x, ty = threadIdx.y;
    int tid = ty * 16 + tx, lr = tid >> 5, lk = tid & 31;
    int kc1 = split * CPS + CPS; if (kc1 > KC) kc1 = KC;
    for (int kc = split * CPS; kc < kc1; ++kc) {
        int co = chunk_off(att, kc);
#pragma unroll
        for (int r = 0; r < 4; ++r) {
            int row = lr + r * 8;
            Qa[row][lk] = q [row_base(att, b, mt + row) + co + lk];
            Ka[row][lk] = kv[row_base(att, b, nt + row) + co + lk];
        }
        __syncthreads();
#pragma unroll
        for (int kk = 0; kk < 32; ++kk) {
            float a0 = Qa[ty][kk], a1 = Qa[ty + 16][kk];
            float b0 = Ka[tx][kk], b1 = Ka[tx + 16][kk];
            acc[0][0] += a0 * b0; acc[0][1] += a0 * b1;
            acc[1][0] += a1 * b0; acc[1][1] += a1 * b1;
        }
        __syncthreads();
    }
    float* dst = Spart + ((long)(b * ntiles + t) * nsplit + split) * 1024;
#pragma unroll
    for (int ii = 0; ii < 2; ++ii)
#pragma unroll
        for (int jj = 0; jj < 2; ++jj)
            dst[(ty + ii * 16) * 32 + tx + jj * 16] = acc[ii][jj];
}

// ---------------- K3c: reduce splits, apply norms + causal mask -----------
__global__ __launch_bounds__(256) void k_sreduce(
        const float* __restrict__ Spart, const float* __restrict__ nq,
        const float* __restrict__ nk, float* __restrict__ S,
        int M, int nsplit, int ntiles) {
    // grid (ntiles, 4)
    int t = blockIdx.x, b = blockIdx.y;
    int i = 0;
    while (t >= (i + 1) * (i + 2) / 2) ++i;
    int j = t - i * (i + 1) / 2;
    const float* src = Spart + (long)(b * ntiles + t) * nsplit * 1024;
    for (int e = threadIdx.x; e < 1024; e += 256) {
        float s = 0.f;
        for (int sp = 0; sp < nsplit; ++sp) s += src[sp * 1024 + e];
        int m = i * 32 + (e >> 5), n = j * 32 + (e & 31);
        float v = (n <= m) ? s / (nq[b * M + m] * nk[b * M + n]) : 0.f;
        S[((long)b * M + m) * M + n] = v;
    }
}

// ---------------- K4: causal softmax, zero-fill n>m -----------------------
__global__ __launch_bounds__(256) void k_softmax(float* __restrict__ S, int M) {
    // grid (M, 4)
    int m = blockIdx.x, b = blockIdx.y;
    float* row = S + ((long)b * M + m) * M;
    int len = m + 1;
    __shared__ float red[256];
    float mx = -1e30f;
    for (int i = threadIdx.x; i < len; i += 256) mx = fmaxf(mx, row[i]);
    red[threadIdx.x] = mx; __syncthreads();
    for (int w = 128; w >= 1; w >>= 1) {
        if (threadIdx.x < w) red[threadIdx.x] = fmaxf(red[threadIdx.x], red[threadIdx.x + w]);
        __syncthreads();
    }
    mx = red[0]; __syncthreads();
    float sum = 0.f;
    for (int i = threadIdx.x; i < len; i += 256) {
        float e = expf(row[i] - mx); row[i] = e; sum += e;
    }
    red[threadIdx.x] = sum; __syncthreads();
    for (int w = 128; w >= 1; w >>= 1) {
        if (threadIdx.x < w) red[threadIdx.x] += red[threadIdx.x + w];
        __syncthreads();
    }
    float inv = 1.f / red[0];
    for (int i = threadIdx.x; i < len; i += 256) row[i] *= inv;
    for (int i = len + threadIdx.x; i < M; i += 256) row[i] = 0.f;
}

// ---------------- K5: O = P @ V, unfold + residual into cat ---------------
__global__ __launch_bounds__(256) void k_ogemm(
        const float* __restrict__ P, const float* __restrict__ kv,
        float* __restrict__ cat, int att, int M, int KC) {
    // grid (M/32, KC, 4), block (16,16)
    int mt = blockIdx.x * 32, kc = blockIdx.y, b = blockIdx.z;
    int co = chunk_off(att, kc);
    __shared__ float Pa[32][33], Va[32][33];
    float acc[2][2] = {};
    int tx = threadIdx.x, ty = threadIdx.y;
    int tid = ty * 16 + tx, lr = tid >> 5, lk = tid & 31;
    int nmax = mt + 32; if (nmax > M) nmax = M;
    for (int nt = 0; nt < nmax; nt += 32) {
#pragma unroll
        for (int r = 0; r < 4; ++r) {
            int row = lr + r * 8;
            Pa[row][lk] = P[((long)b * M + mt + row) * M + nt + lk];
            Va[row][lk] = kv[row_base(att, b, nt + row) + co + lk];
        }
        __syncthreads();
#pragma unroll
        for (int kk = 0; kk < 32; ++kk) {
            float a0 = Pa[ty][kk], a1 = Pa[ty + 16][kk];
            float b0 = Va[kk][tx], b1 = Va[kk][tx + 16];
            acc[0][0] += a0 * b0; acc[0][1] += a0 * b1;
            acc[1][0] += a1 * b0; acc[1][1] += a1 * b1;
        }
        __syncthreads();
    }
#pragma unroll
    for (int i = 0; i < 2; ++i)
#pragma unroll
        for (int j = 0; j < 2; ++j) {
            int m = mt + ty + i * 16, k = tx + j * 16;
            int adr = row_base(att, b, m) + co + k;
            cat[adr] = acc[i][j] + kv[adr];   // residual: + tv (kv part)
        }
}

// ---------------- K6: transpose cat (b,d,s) -> ct (token, d) --------------
__global__ __launch_bounds__(256) void k_transpose(
        const float* __restrict__ cat, float* __restrict__ ct) {
    // grid (32, 4, 100), block (32, 8)
    __shared__ float t[32][33];
    int hwt = blockIdx.x * 32, dt = blockIdx.y * 32, bn = blockIdx.z;
    int b = bn / 25, uv = bn - b * 25;
    const float* src = cat + (long)b * 128 * NSP + uv * HWC;
    for (int r = threadIdx.y; r < 32; r += 8)
        t[r][threadIdx.x] = src[(dt + r) * NSP + hwt + threadIdx.x];
    __syncthreads();
    float* dst = ct + (long)bn * HWC * 128;
    for (int r = threadIdx.y; r < 32; r += 8)
        dst[(hwt + r) * 128 + dt + threadIdx.x] = t[threadIdx.x][r];
}

// ---------------- K7: LayerNorm stats -------------------------------------
__global__ __launch_bounds__(256) void k_lnstats(
        const float* __restrict__ ct, float* __restrict__ mu, float* __restrict__ rstd) {
    // grid (25600), 4 waves/block, one token per wave
    int t = blockIdx.x * 4 + (threadIdx.x >> 6);
    int lane = threadIdx.x & 63;
    const float* row = ct + (long)t * 128;
    float v0 = row[lane], v1 = row[lane + 64];
    float s = v0 + v1, s2 = v0 * v0 + v1 * v1;
    for (int o = 32; o >= 1; o >>= 1) { s += __shfl_down(s, o); s2 += __shfl_down(s2, o); }
    if (lane == 0) {
        float m = s * (1.f / 128.f);
        float var = s2 * (1.f / 128.f) - m * m;
        mu[t] = m; rstd[t] = rsqrtf(var + 1e-5f);
    }
}

// ---------------- K8: h1 = relu(LN(ct) @ W1) ------------------------------
__global__ __launch_bounds__(256) void k_mlp1(
        const float* __restrict__ ct, const float* __restrict__ mu,
        const float* __restrict__ rstd, const float* __restrict__ g,
        const float* __restrict__ be, const float* __restrict__ W1,
        float* __restrict__ h1) {
    // grid (3200, 4), block (16,16)
    int tt = blockIdx.x * 32, nt = blockIdx.y * 32;
    __shared__ float Aa[32][33], Bb[32][33];
    int tx = threadIdx.x, ty = threadIdx.y;
    int tid = ty * 16 + tx, lr = tid >> 5, lk = tid & 31;
    float acc[2][2] = {};
    for (int kc = 0; kc < 128; kc += 32) {
#pragma unroll
        for (int r = 0; r < 4; ++r) {
            int row = lr + r * 8;
            int t = tt + row;
            float x = ct[(long)t * 128 + kc + lk];
            Aa[row][lk] = (x - mu[t]) * rstd[t] * g[kc + lk] + be[kc + lk];
            Bb[row][lk] = W1[(kc + row) * 128 + nt + lk];
        }
        __syncthreads();
#pragma unroll
        for (int kk = 0; kk < 32; ++kk) {
            float a0 = Aa[ty][kk], a1 = Aa[ty + 16][kk];
            float b0 = Bb[kk][tx], b1 = Bb[kk][tx + 16];
            acc[0][0] += a0 * b0; acc[0][1] += a0 * b1;
            acc[1][0] += a1 * b0; acc[1][1] += a1 * b1;
        }
        __syncthreads();
    }
#pragma unroll
    for (int i = 0; i < 2; ++i)
#pragma unroll
        for (int j = 0; j < 2; ++j) {
            int t = tt + ty + i * 16, n = nt + tx + j * 16;
            h1[(long)t * 128 + n] = fmaxf(acc[i][j], 0.f);
        }
}

// ---------------- K9: m2 = h1 @ W2 + ct -----------------------------------
__global__ __launch_bounds__(256) void k_mlp2(
        const float* __restrict__ h1, const float* __restrict__ ct,
        const float* __restrict__ W2, float* __restrict__ m2) {
    int tt = blockIdx.x * 32, nt = blockIdx.y * 32;
    __shared__ float Aa[32][33], Bb[32][33];
    int tx = threadIdx.x, ty = threadIdx.y;
    int tid = ty * 16 + tx, lr = tid >> 5, lk = tid & 31;
    float acc[2][2] = {};
    for (int kc = 0; kc < 128; kc += 32) {
#pragma unroll
        for (int r = 0; r < 4; ++r) {
            int row = lr + r * 8;
            Aa[row][lk] = h1[(long)(tt + row) * 128 + kc + lk];
            Bb[row][lk] = W2[(kc + row) * 128 + nt + lk];
        }
        __syncthreads();
#pragma unroll
        for (int kk = 0; kk < 32; ++kk) {
            float a0 = Aa[ty][kk], a1 = Aa[ty + 16][kk];
            float b0 = Bb[kk][tx], b1 = Bb[kk][tx + 16];
            acc[0][0] += a0 * b0; acc[0][1] += a0 * b1;
            acc[1][0] += a1 * b0; acc[1][1] += a1 * b1;
        }
        __syncthreads();
    }
#pragma unroll
    for (int i = 0; i < 2; ++i)
#pragma unroll
        for (int j = 0; j < 2; ++j) {
            int t = tt + ty + i * 16, n = nt + tx + j * 16;
            m2[(long)t * 128 + n] = acc[i][j] + ct[(long)t * 128 + n];
        }
}

// ---------------- K10: out = m2 @ W_out, scatter to (b,64,25,32,32) -------
__global__ __launch_bounds__(256) void k_out(
        const float* __restrict__ m2, const float* __restrict__ Wo,
        float* __restrict__ out) {
    // grid (3200, 2), block (16,16); tokens along tx for coalesced stores
    int tt = blockIdx.x * 32, ot = blockIdx.y * 32;
    __shared__ float Aa[32][33], Bb[32][33];
    int tx = threadIdx.x, ty = threadIdx.y;
    int tid = ty * 16 + tx, lr = tid >> 5, lk = tid & 31;
    float acc[2][2] = {};
    for (int kc = 0; kc < 128; kc += 32) {
#pragma unroll
        for (int r = 0; r < 4; ++r) {
            int row = lr + r * 8;
            Aa[row][lk] = m2[(long)(tt + row) * 128 + kc + lk];
            Bb[row][lk] = Wo[(kc + row) * 64 + ot + lk];
        }
        __syncthreads();
#pragma unroll
        for (int kk = 0; kk < 32; ++kk) {
            float a0 = Aa[tx][kk], a1 = Aa[tx + 16][kk];  // token along tx
            float b0 = Bb[kk][ty], b1 = Bb[kk][ty + 16];  // o along ty
            acc[0][0] += a0 * b0; acc[0][1] += a0 * b1;
            acc[1][0] += a1 * b0; acc[1][1] += a1 * b1;
        }
        __syncthreads();
    }
#pragma unroll
    for (int i = 0; i < 2; ++i)
#pragma unroll
        for (int j = 0; j < 2; ++j) {
            int t = tt + tx + i * 16, o = ot + ty + j * 16;
            int bn = t >> 10, hw = t & 1023;
            int b = bn / 25, uv = bn - b * 25;
            out[((b * 64 + o) * 25 + uv) * 1024 + hw] = acc[i][j];
        }
}

// ---------------- launch ---------------------------------------------------
extern "C" void kernel_launch(void* const* d_in, const int* in_sizes, int n_in,
                              void* d_out, int out_size, void* d_ws, size_t ws_size,
                              hipStream_t stream) {
    const float* x_lf = (const float*)d_in[0];
    const float* x_hf = (const float*)d_in[1];
    const float* W_in = (const float*)d_in[2];
    const float* W_kv = (const float*)d_in[3];
    const float* ln_g = (const float*)d_in[4];
    const float* ln_b = (const float*)d_in[5];
    const float* W_m1 = (const float*)d_in[6];
    const float* W_m2 = (const float*)d_in[7];
    const float* W_ot = (const float*)d_in[8];
    float* out = (float*)d_out;

    float* ws  = (float*)d_ws;
    float* q    = ws;                    // 13,107,200
    float* kv   = ws + 13107200;         // 13,107,200
    float* cat  = ws + 26214400;         // 13,107,200
    float* S    = ws + 39321600;         // 4,194,304 (att0 needs all of it)
    float* nq   = ws + 43515904;         // 4096
    float* nk   = nq + 4096;             // 4096
    float* mu   = nk + 4096;             // 102400
    float* rstd = mu + 102400;           // 102400
    float* ct   = q;                     // reuse: q dead after attention
    float* h1   = kv;                    // reuse: kv dead after attention
    float* m2   = cat;                   // reuse: cat dead after transpose
    // att1/att2 use only 4*160*160=102,400 floats of S; park split-K partials
    // in the tail of the S allocation (max 4*15*40*1024 = 2,457,600 floats).
    float* Spart = S + 262144;

    // 1. token GEMMs
    k_tokens<<<dim3(100, 4, 2), 256, 0, stream>>>(x_hf, x_lf, W_in, W_kv, q, kv);

    // 2. three attentions
    const int Ms[3]  = {1024, 160, 160};
    const int KCs[3] = {25, 160, 320};
    for (int att = 0; att < 3; ++att) {
        int M = Ms[att], KC = KCs[att], MT = M / 32;
        k_norms<<<dim3(M, 4), 256, 0, stream>>>(q,  nq, att, M, KC);
        k_norms<<<dim3(M, 4), 256, 0, stream>>>(kv, nk, att, M, KC);
        if (att == 0) {
            k_sgemm<<<dim3(MT, MT, 4), dim3(16, 16), 0, stream>>>(q, kv, nq, nk, S, att, M, KC);
        } else {
            const int CPS = 8;
            int nsplit = (KC + CPS - 1) / CPS;          // att1: 20, att2: 40
            int ntiles = MT * (MT + 1) / 2;             // 15
            k_sgemm_split<<<dim3(ntiles, nsplit, 4), dim3(16, 16), 0, stream>>>(
                q, kv, Spart, att, M, KC, CPS, nsplit, ntiles);
            k_sreduce<<<dim3(ntiles, 4), 256, 0, stream>>>(
                Spart, nq, nk, S, M, nsplit, ntiles);
        }
        k_softmax<<<dim3(M, 4), 256, 0, stream>>>(S, M);
        k_ogemm<<<dim3(MT, KC, 4), dim3(16, 16), 0, stream>>>(S, kv, cat, att, M, KC);
    }

    // 3. transpose to token-major
    k_transpose<<<dim3(32, 4, 100), dim3(32, 8), 0, stream>>>(cat, ct);

    // 4. LN + MLP + out projection
    k_lnstats<<<dim3(25600), 256, 0, stream>>>(ct, mu, rstd);
    k_mlp1<<<dim3(3200, 4), dim3(16, 16), 0, stream>>>(ct, mu, rstd, ln_g, ln_b, W_m1, h1);
    k_mlp2<<<dim3(3200, 4), dim3(16, 16), 0, stream>>>(h1, ct, W_m2, m2);
    k_out <<<dim3(3200, 2), dim3(16, 16), 0, stream>>>(m2, W_ot, out);
}

// Round 3
// 613.663 us; speedup vs baseline: 4.8989x; 2.2528x over previous
//
#include <hip/hip_runtime.h>

#define NSP   25600   // 25*32*32 spatial elems per (b, channel)
#define HWC   1024    // 32*32

typedef __attribute__((ext_vector_type(8))) short bf8;   // 8 bf16 = 4 VGPRs
typedef __attribute__((ext_vector_type(4))) float f4;    // MFMA C/D frag
#define MFMA(a,b,c) __builtin_amdgcn_mfma_f32_16x16x32_bf16(a, b, c, 0, 0, 0)
typedef unsigned short u16;

__device__ __forceinline__ u16 f2b(float f) {
    union { float f; unsigned u; } v; v.f = f;
    unsigned r = v.u + 0x7fffu + ((v.u >> 16) & 1u);
    return (u16)(r >> 16);
}
__device__ __forceinline__ float b2f(u16 h) {
    union { unsigned u; float f; } v; v.u = ((unsigned)h) << 16;
    return v.f;
}

// Attention addressing (K re-chunked into 32-contig-float blocks; legal since
// fold K-order only needs consistency between q/k/v/unfold).
__device__ __forceinline__ long row_base(int att, int b, int m) {
    if (att == 0) { int cc = m >> 5, h = m & 31;   return ((long)(b*128 + cc))*NSP + h*32; }
    else if (att == 1) { int cc = m / 5, u = m - cc*5; return ((long)(b*128 + 32 + cc))*NSP + u*5120; }
    else { int h = m / 5, u = m - h*5;            return ((long)(b*128 + 64))*NSP + u*5120 + h*32; }
}
__device__ __forceinline__ long chunk_off(int att, int kc) {
    if (att == 0) return (long)kc * 1024;
    else if (att == 1) return (long)kc * 32;
    else { int cc = kc / 5, v = kc - cc*5; return (long)cc*NSP + v*1024; }
}

// ---------------- K1: token GEMMs (MFMA) -> bf16 q / kv --------------------
__global__ __launch_bounds__(256) void k_tokens(
        const float* __restrict__ x_hf, const float* __restrict__ x_lf,
        const float* __restrict__ W_in, const float* __restrict__ W_kv,
        u16* __restrict__ qb, u16* __restrict__ kvb) {
    // grid (400, 4, 2)
    int s0 = blockIdx.x * 64, b = blockIdx.y, which = blockIdx.z;
    const float* x  = which ? x_lf : x_hf;
    const float* Wt = which ? W_kv : W_in;
    u16* out = which ? kvb : qb;
    __shared__ u16 Axs[64 * 72];   // [token][c]
    __shared__ u16 Wl [128 * 72];  // [d][c]
    int tid = threadIdx.x;
    for (int idx = tid; idx < 8192; idx += 256) {      // W transpose-stage
        int c = idx >> 7, dd = idx & 127;
        Wl[dd * 72 + c] = f2b(Wt[idx]);
    }
    for (int idx = tid; idx < 4096; idx += 256) {      // x transpose-stage
        int c = idx >> 6, s = idx & 63;
        Axs[s * 72 + c] = f2b(x[(long)(b * 64 + c) * NSP + s0 + s]);
    }
    __syncthreads();
    int w = tid >> 6, l = tid & 63, quad = l >> 4, col = l & 15;
    f4 z = {0.f, 0.f, 0.f, 0.f};
    f4 acc[8]; for (int i = 0; i < 8; ++i) acc[i] = z;
#pragma unroll
    for (int kc = 0; kc < 2; ++kc) {
        bf8 a = *(bf8*)&Axs[(w * 16 + col) * 72 + kc * 32 + quad * 8];
#pragma unroll
        for (int nt = 0; nt < 8; ++nt) {
            bf8 bb = *(bf8*)&Wl[(nt * 16 + col) * 72 + kc * 32 + quad * 8];
            acc[nt] = MFMA(a, bb, acc[nt]);
        }
    }
#pragma unroll
    for (int nt = 0; nt < 8; ++nt) {
        int d = nt * 16 + col;
        long base = ((long)(b * 128 + d)) * NSP + s0 + w * 16 + quad * 4;
        ushort4 pk;
        pk.x = f2b(acc[nt][0]); pk.y = f2b(acc[nt][1]);
        pk.z = f2b(acc[nt][2]); pk.w = f2b(acc[nt][3]);
        *(ushort4*)(out + base) = pk;
    }
}

// ---------------- K2: row L2 norms (bf16 src) ------------------------------
__global__ __launch_bounds__(256) void k_norms(
        const u16* __restrict__ src, float* __restrict__ dst,
        int att, int M, int KC) {
    int m = blockIdx.x, b = blockIdx.y;
    long base = row_base(att, b, m);
    float s = 0.f;
    int K = KC * 32;
    for (int k = threadIdx.x; k < K; k += 256) {
        float v = b2f(src[base + chunk_off(att, k >> 5) + (k & 31)]);
        s += v * v;
    }
    __shared__ float red[256];
    red[threadIdx.x] = s; __syncthreads();
    for (int w = 128; w >= 1; w >>= 1) {
        if (threadIdx.x < w) red[threadIdx.x] += red[threadIdx.x + w];
        __syncthreads();
    }
    if (threadIdx.x == 0) dst[b * M + m] = fmaxf(sqrtf(red[0]), 1e-12f);
}

// ---------------- K3a: att0 S-GEMM (MFMA, 64x64 tile) ----------------------
__global__ __launch_bounds__(256) void k_sgemm0(
        const u16* __restrict__ qb, const u16* __restrict__ kvb,
        const float* __restrict__ nq, const float* __restrict__ nk,
        float* __restrict__ S) {
    // grid (16,16,4)
    if (blockIdx.y > blockIdx.x) return;
    int mt = blockIdx.x * 64, nt = blockIdx.y * 64, b = blockIdx.z;
    __shared__ u16 Qs[64 * 40], Ks[64 * 40];
    int tid = threadIdx.x, w = tid >> 6, l = tid & 63, quad = l >> 4, col = l & 15;
    int srow = tid >> 2, g = tid & 3;
    f4 z = {0.f, 0.f, 0.f, 0.f};
    f4 acc[4]; for (int i = 0; i < 4; ++i) acc[i] = z;
    for (int kc = 0; kc < 25; ++kc) {
        long co = (long)kc * 1024;
        {
            int m = mt + srow;
            *(bf8*)&Qs[srow * 40 + g * 8] =
                *(const bf8*)(qb + ((long)(b*128 + (m >> 5)))*NSP + (m & 31)*32 + co + g*8);
            int n = nt + srow;
            *(bf8*)&Ks[srow * 40 + g * 8] =
                *(const bf8*)(kvb + ((long)(b*128 + (n >> 5)))*NSP + (n & 31)*32 + co + g*8);
        }
        __syncthreads();
        bf8 a = *(bf8*)&Qs[(w * 16 + col) * 40 + quad * 8];
#pragma unroll
        for (int t2 = 0; t2 < 4; ++t2) {
            bf8 bb = *(bf8*)&Ks[(t2 * 16 + col) * 40 + quad * 8];
            acc[t2] = MFMA(a, bb, acc[t2]);
        }
        __syncthreads();
    }
#pragma unroll
    for (int t2 = 0; t2 < 4; ++t2)
#pragma unroll
        for (int r = 0; r < 4; ++r) {
            int m = mt + w * 16 + quad * 4 + r, n = nt + t2 * 16 + col;
            float v = (n <= m) ? acc[t2][r] / (nq[b*1024 + m] * nk[b*1024 + n]) : 0.f;
            S[((long)b * 1024 + m) * 1024 + n] = v;
        }
}

// ---------------- K3b: att1/2 split-K S-GEMM (MFMA, LDS-free) --------------
__global__ __launch_bounds__(256) void k_sgemm_split(
        const u16* __restrict__ qb, const u16* __restrict__ kvb,
        float* __restrict__ Spart, int att, int nslots) {
    // grid (15, nsplit, 4); block 256 = 4 waves; CPS=16 chunks/block
    int t = blockIdx.x, split = blockIdx.y, b = blockIdx.z;
    int i = 0;
    while (t >= (i + 1) * (i + 2) / 2) ++i;
    int j = t - i * (i + 1) / 2;
    int mt = i * 32, nt = j * 32;
    int tid = threadIdx.x, w = tid >> 6, l = tid & 63, quad = l >> 4, col = l & 15;
    long rm0 = row_base(att, b, mt + col),      rm1 = row_base(att, b, mt + 16 + col);
    long rn0 = row_base(att, b, nt + col),      rn1 = row_base(att, b, nt + 16 + col);
    int ko = quad * 8;
    f4 z = {0.f, 0.f, 0.f, 0.f};
    f4 a00 = z, a01 = z, a10 = z, a11 = z;
#pragma unroll
    for (int s = 0; s < 4; ++s) {
        int kc = split * 16 + w * 4 + s;
        long co = chunk_off(att, kc);
        bf8 qa0 = *(const bf8*)(qb + rm0 + co + ko);
        bf8 qa1 = *(const bf8*)(qb + rm1 + co + ko);
        bf8 kb0 = *(const bf8*)(kvb + rn0 + co + ko);
        bf8 kb1 = *(const bf8*)(kvb + rn1 + co + ko);
        a00 = MFMA(qa0, kb0, a00); a01 = MFMA(qa0, kb1, a01);
        a10 = MFMA(qa1, kb0, a10); a11 = MFMA(qa1, kb1, a11);
    }
    int sp = split * 4 + w;
    float* dst = Spart + ((long)((b * 15 + t) * nslots + sp)) * 1024;
#pragma unroll
    for (int r = 0; r < 4; ++r) {
        dst[(quad * 4 + r) * 32 + col]            = a00[r];
        dst[(quad * 4 + r) * 32 + 16 + col]       = a01[r];
        dst[(16 + quad * 4 + r) * 32 + col]       = a10[r];
        dst[(16 + quad * 4 + r) * 32 + 16 + col]  = a11[r];
    }
}

// ---------------- K3c: reduce splits + norms + mask ------------------------
__global__ __launch_bounds__(256) void k_sreduce(
        const float* __restrict__ Spart, const float* __restrict__ nq,
        const float* __restrict__ nk, float* __restrict__ S,
        int M, int nslots) {
    // grid (15, 4)
    int t = blockIdx.x, b = blockIdx.y;
    int i = 0;
    while (t >= (i + 1) * (i + 2) / 2) ++i;
    int j = t - i * (i + 1) / 2;
    const float* src = Spart + (long)(b * 15 + t) * nslots * 1024;
    for (int e = threadIdx.x; e < 1024; e += 256) {
        float s = 0.f;
        for (int sp = 0; sp < nslots; ++sp) s += src[sp * 1024 + e];
        int m = i * 32 + (e >> 5), n = j * 32 + (e & 31);
        float v = (n <= m) ? s / (nq[b * M + m] * nk[b * M + n]) : 0.f;
        S[((long)b * M + m) * M + n] = v;
    }
}

// ---------------- K4: causal softmax (fp32 in-place + bf16 copy) -----------
__global__ __launch_bounds__(256) void k_softmax(
        float* __restrict__ S, u16* __restrict__ Pb, int M) {
    int m = blockIdx.x, b = blockIdx.y;
    float* row = S + ((long)b * M + m) * M;
    u16*   pr  = Pb + ((long)b * M + m) * M;
    int len = m + 1;
    __shared__ float red[256];
    float mx = -1e30f;
    for (int i = threadIdx.x; i < len; i += 256) mx = fmaxf(mx, row[i]);
    red[threadIdx.x] = mx; __syncthreads();
    for (int w = 128; w >= 1; w >>= 1) {
        if (threadIdx.x < w) red[threadIdx.x] = fmaxf(red[threadIdx.x], red[threadIdx.x + w]);
        __syncthreads();
    }
    mx = red[0]; __syncthreads();
    float sum = 0.f;
    for (int i = threadIdx.x; i < len; i += 256) {
        float e = expf(row[i] - mx); row[i] = e; sum += e;
    }
    red[threadIdx.x] = sum; __syncthreads();
    for (int w = 128; w >= 1; w >>= 1) {
        if (threadIdx.x < w) red[threadIdx.x] += red[threadIdx.x + w];
        __syncthreads();
    }
    float inv = 1.f / red[0];
    for (int i = threadIdx.x; i < len; i += 256) {
        float p = row[i] * inv; row[i] = p; pr[i] = f2b(p);
    }
    for (int i = len + threadIdx.x; i < M; i += 256) { row[i] = 0.f; pr[i] = 0; }
}

// ---------------- K5a: att0 O-GEMM (MFMA) + residual -----------------------
__global__ __launch_bounds__(256) void k_ogemm0(
        const u16* __restrict__ Pb, const u16* __restrict__ kvb,
        float* __restrict__ cat) {
    // grid (16, 25, 4): 64 q-rows x one 32-wide feature chunk
    int mt = blockIdx.x * 64, kc = blockIdx.y, b = blockIdx.z;
    long co = (long)kc * 1024;
    __shared__ u16 Ps[64 * 40], Vt[32 * 40];
    int tid = threadIdx.x, w = tid >> 6, l = tid & 63, quad = l >> 4, col = l & 15;
    f4 z = {0.f, 0.f, 0.f, 0.f};
    f4 acc[2]; acc[0] = z; acc[1] = z;
    int nchunks = (mt >> 5) + 2;
    for (int nt2 = 0; nt2 < nchunks; ++nt2) {
        // stage P tile 64x32 (direct, 16B per thread)
        *(bf8*)&Ps[(tid >> 2) * 40 + (tid & 3) * 8] =
            *(const bf8*)(Pb + ((long)b * 1024 + mt + (tid >> 2)) * 1024 + nt2 * 32 + (tid & 3) * 8);
        // stage V transposed: Vt[f][p]
        {
            int p = nt2 * 32 + (tid >> 3), pl = tid >> 3, f = (tid & 7) * 4;
            long rb = ((long)(b * 128 + (p >> 5))) * NSP + (p & 31) * 32 + co;
            ushort4 e = *(const ushort4*)(kvb + rb + f);
            Vt[f * 40 + pl] = e.x; Vt[(f + 1) * 40 + pl] = e.y;
            Vt[(f + 2) * 40 + pl] = e.z; Vt[(f + 3) * 40 + pl] = e.w;
        }
        __syncthreads();
        bf8 a = *(bf8*)&Ps[(w * 16 + col) * 40 + quad * 8];
#pragma unroll
        for (int t2 = 0; t2 < 2; ++t2) {
            bf8 bb = *(bf8*)&Vt[(t2 * 16 + col) * 40 + quad * 8];
            acc[t2] = MFMA(a, bb, acc[t2]);
        }
        __syncthreads();
    }
#pragma unroll
    for (int t2 = 0; t2 < 2; ++t2)
#pragma unroll
        for (int r = 0; r < 4; ++r) {
            int m = mt + w * 16 + quad * 4 + r, f = t2 * 16 + col;
            long adr = ((long)(b * 128 + (m >> 5))) * NSP + (m & 31) * 32 + co + f;
            cat[adr] = acc[t2][r] + b2f(kvb[adr]);
        }
}

// ---------------- K5b: att1/2 O-GEMM (fp32, bf16 V) ------------------------
__global__ __launch_bounds__(256) void k_ogemm12(
        const float* __restrict__ P, const u16* __restrict__ kvb,
        float* __restrict__ cat, int att, int M, int KC) {
    int mt = blockIdx.x * 32, kc = blockIdx.y, b = blockIdx.z;
    long co = chunk_off(att, kc);
    __shared__ float Pa[32][33], Va[32][33];
    float acc[2][2] = {};
    int tx = threadIdx.x & 15, ty = threadIdx.x >> 4;
    int tid = threadIdx.x, lr = tid >> 5, lk = tid & 31;
    int nmax = mt + 32; if (nmax > M) nmax = M;
    for (int nt = 0; nt < nmax; nt += 32) {
#pragma unroll
        for (int r = 0; r < 4; ++r) {
            int row = lr + r * 8;
            Pa[row][lk] = P[((long)b * M + mt + row) * M + nt + lk];
            Va[row][lk] = b2f(kvb[row_base(att, b, nt + row) + co + lk]);
        }
        __syncthreads();
#pragma unroll
        for (int kk = 0; kk < 32; ++kk) {
            float a0 = Pa[ty][kk], a1 = Pa[ty + 16][kk];
            float b0 = Va[kk][tx], b1 = Va[kk][tx + 16];
            acc[0][0] += a0 * b0; acc[0][1] += a0 * b1;
            acc[1][0] += a1 * b0; acc[1][1] += a1 * b1;
        }
        __syncthreads();
    }
#pragma unroll
    for (int i = 0; i < 2; ++i)
#pragma unroll
        for (int j = 0; j < 2; ++j) {
            int m = mt + ty + i * 16, k = tx + j * 16;
            long adr = row_base(att, b, m) + co + k;
            cat[adr] = acc[i][j] + b2f(kvb[adr]);
        }
}

// ---------------- K6: transpose cat (b,d,s) -> ct (token, d) ---------------
__global__ __launch_bounds__(256) void k_transpose(
        const float* __restrict__ cat, float* __restrict__ ct) {
    __shared__ float t[32][33];
    int hwt = blockIdx.x * 32, dt = blockIdx.y * 32, bn = blockIdx.z;
    int b = bn / 25, uv = bn - b * 25;
    const float* src = cat + (long)b * 128 * NSP + uv * HWC;
    int tx = threadIdx.x & 31, ty = threadIdx.x >> 5;
    for (int r = ty; r < 32; r += 8)
        t[r][tx] = src[(long)(dt + r) * NSP + hwt + tx];
    __syncthreads();
    float* dst = ct + (long)bn * HWC * 128;
    for (int r = ty; r < 32; r += 8)
        dst[(long)(hwt + r) * 128 + dt + tx] = t[tx][r];
}

// ---------------- K7: LayerNorm stats --------------------------------------
__global__ __launch_bounds__(256) void k_lnstats(
        const float* __restrict__ ct, float* __restrict__ mu, float* __restrict__ rstd) {
    int t = blockIdx.x * 4 + (threadIdx.x >> 6);
    int lane = threadIdx.x & 63;
    const float* row = ct + (long)t * 128;
    float v0 = row[lane], v1 = row[lane + 64];
    float s = v0 + v1, s2 = v0 * v0 + v1 * v1;
    for (int o = 32; o >= 1; o >>= 1) { s += __shfl_down(s, o); s2 += __shfl_down(s2, o); }
    if (lane == 0) {
        float m = s * (1.f / 128.f);
        float var = s2 * (1.f / 128.f) - m * m;
        mu[t] = m; rstd[t] = rsqrtf(var + 1e-5f);
    }
}

// ---------------- K8: h1 = relu(LN(ct) @ W1) (MFMA) ------------------------
__global__ __launch_bounds__(256) void k_mlp1(
        const float* __restrict__ ct, const float* __restrict__ mu,
        const float* __restrict__ rstd, const float* __restrict__ g,
        const float* __restrict__ be, const float* __restrict__ W1,
        u16* __restrict__ h1b) {
    // grid (1600)
    int tt = blockIdx.x * 64, tid = threadIdx.x;
    __shared__ u16 As[64 * 136], Wt[128 * 136];
    for (int idx = tid; idx < 16384; idx += 256) {
        int k = idx >> 7, n = idx & 127;
        Wt[n * 136 + k] = f2b(W1[idx]);
    }
    for (int idx = tid; idx < 8192; idx += 256) {
        int row = idx >> 7, k = idx & 127, t = tt + row;
        float v = (ct[(long)t * 128 + k] - mu[t]) * rstd[t] * g[k] + be[k];
        As[row * 136 + k] = f2b(v);
    }
    __syncthreads();
    int w = tid >> 6, l = tid & 63, quad = l >> 4, col = l & 15;
    f4 z = {0.f, 0.f, 0.f, 0.f};
    f4 acc[8]; for (int i = 0; i < 8; ++i) acc[i] = z;
#pragma unroll
    for (int kc = 0; kc < 4; ++kc) {
        bf8 a = *(bf8*)&As[(w * 16 + col) * 136 + kc * 32 + quad * 8];
#pragma unroll
        for (int nt = 0; nt < 8; ++nt) {
            bf8 bb = *(bf8*)&Wt[(nt * 16 + col) * 136 + kc * 32 + quad * 8];
            acc[nt] = MFMA(a, bb, acc[nt]);
        }
    }
#pragma unroll
    for (int nt = 0; nt < 8; ++nt)
#pragma unroll
        for (int r = 0; r < 4; ++r) {
            int t = tt + w * 16 + quad * 4 + r, n = nt * 16 + col;
            h1b[(long)t * 128 + n] = f2b(fmaxf(acc[nt][r], 0.f));
        }
}

// ---------------- K9: m2 = h1 @ W2 + ct (MFMA) -----------------------------
__global__ __launch_bounds__(256) void k_mlp2(
        const u16* __restrict__ h1b, const float* __restrict__ ct,
        const float* __restrict__ W2, u16* __restrict__ m2b) {
    int tt = blockIdx.x * 64, tid = threadIdx.x;
    __shared__ u16 As[64 * 136], Wt[128 * 136];
    for (int idx = tid; idx < 16384; idx += 256) {
        int k = idx >> 7, n = idx & 127;
        Wt[n * 136 + k] = f2b(W2[idx]);
    }
    for (int idx = tid; idx < 2048; idx += 256) {
        int row = idx >> 5, kg = (idx & 31) * 4;
        *(ushort4*)&As[row * 136 + kg] = *(const ushort4*)(h1b + (long)(tt + row) * 128 + kg);
    }
    __syncthreads();
    int w = tid >> 6, l = tid & 63, quad = l >> 4, col = l & 15;
    f4 z = {0.f, 0.f, 0.f, 0.f};
    f4 acc[8]; for (int i = 0; i < 8; ++i) acc[i] = z;
#pragma unroll
    for (int kc = 0; kc < 4; ++kc) {
        bf8 a = *(bf8*)&As[(w * 16 + col) * 136 + kc * 32 + quad * 8];
#pragma unroll
        for (int nt = 0; nt < 8; ++nt) {
            bf8 bb = *(bf8*)&Wt[(nt * 16 + col) * 136 + kc * 32 + quad * 8];
            acc[nt] = MFMA(a, bb, acc[nt]);
        }
    }
#pragma unroll
    for (int nt = 0; nt < 8; ++nt)
#pragma unroll
        for (int r = 0; r < 4; ++r) {
            int t = tt + w * 16 + quad * 4 + r, n = nt * 16 + col;
            m2b[(long)t * 128 + n] = f2b(acc[nt][r] + ct[(long)t * 128 + n]);
        }
}

// ---------------- K10: out = m2 @ W_out (MFMA), scatter --------------------
__global__ __launch_bounds__(256) void k_out(
        const u16* __restrict__ m2b, const float* __restrict__ Wo,
        float* __restrict__ out) {
    int tt = blockIdx.x * 64, tid = threadIdx.x;
    __shared__ u16 As[64 * 136], Wt[64 * 136];
    for (int idx = tid; idx < 8192; idx += 256) {
        int k = idx >> 6, o = idx & 63;
        Wt[o * 136 + k] = f2b(Wo[idx]);
    }
    for (int idx = tid; idx < 2048; idx += 256) {
        int row = idx >> 5, kg = (idx & 31) * 4;
        *(ushort4*)&As[row * 136 + kg] = *(const ushort4*)(m2b + (long)(tt + row) * 128 + kg);
    }
    __syncthreads();
    int w = tid >> 6, l = tid & 63, quad = l >> 4, col = l & 15;
    f4 z = {0.f, 0.f, 0.f, 0.f};
    f4 acc[4]; for (int i = 0; i < 4; ++i) acc[i] = z;
#pragma unroll
    for (int kc = 0; kc < 4; ++kc) {
        bf8 a = *(bf8*)&As[(w * 16 + col) * 136 + kc * 32 + quad * 8];
#pragma unroll
        for (int nt = 0; nt < 4; ++nt) {
            bf8 bb = *(bf8*)&Wt[(nt * 16 + col) * 136 + kc * 32 + quad * 8];
            acc[nt] = MFMA(a, bb, acc[nt]);
        }
    }
    int t0 = tt + w * 16 + quad * 4;
    int bn = t0 >> 10, hw = t0 & 1023;
    int b = bn / 25, uv = bn - b * 25;
#pragma unroll
    for (int nt = 0; nt < 4; ++nt) {
        int o = nt * 16 + col;
        float4 pk = {acc[nt][0], acc[nt][1], acc[nt][2], acc[nt][3]};
        *(float4*)(out + ((long)((b * 64 + o) * 25 + uv)) * 1024 + hw) = pk;
    }
}

// ---------------- launch ---------------------------------------------------
extern "C" void kernel_launch(void* const* d_in, const int* in_sizes, int n_in,
                              void* d_out, int out_size, void* d_ws, size_t ws_size,
                              hipStream_t stream) {
    const float* x_lf = (const float*)d_in[0];
    const float* x_hf = (const float*)d_in[1];
    const float* W_in = (const float*)d_in[2];
    const float* W_kv = (const float*)d_in[3];
    const float* ln_g = (const float*)d_in[4];
    const float* ln_b = (const float*)d_in[5];
    const float* W_m1 = (const float*)d_in[6];
    const float* W_m2 = (const float*)d_in[7];
    const float* W_ot = (const float*)d_in[8];
    float* out = (float*)d_out;

    float* ws = (float*)d_ws;
    // [0, 13.1M): attention-phase Pb (2.1M) + Spart (4.9M); later ct fp32 (13.1M)
    u16*   Pb    = (u16*)ws;                          // 4*1024*1024 bf16
    float* Spart = ws + 2097152;                      // up to 4*15*80*1024 fp32
    float* ct    = ws;                                // after attention
    float* cat   = ws + 13107200;                     // 13.1M fp32
    u16*   m2b   = (u16*)(ws + 13107200);             // after transpose (over cat)
    u16*   qb    = (u16*)(ws + 26214400);             // 13.1M bf16
    u16*   h1b   = (u16*)(ws + 26214400);             // after attention (over qb)
    u16*   kvb   = (u16*)(ws + 32768000);             // 13.1M bf16
    float* S     = ws + 39321600;                     // 4.19M fp32
    float* nq    = ws + 43515904;
    float* nk    = nq + 4096;
    float* mu    = nk + 4096;
    float* rstd  = mu + 102400;

    // 1. token GEMMs -> bf16 q/kv
    k_tokens<<<dim3(400, 4, 2), 256, 0, stream>>>(x_hf, x_lf, W_in, W_kv, qb, kvb);

    // 2. three attentions
    const int Ms[3]  = {1024, 160, 160};
    const int KCs[3] = {25, 160, 320};
    for (int att = 0; att < 3; ++att) {
        int M = Ms[att], KC = KCs[att];
        k_norms<<<dim3(M, 4), 256, 0, stream>>>(qb,  nq, att, M, KC);
        k_norms<<<dim3(M, 4), 256, 0, stream>>>(kvb, nk, att, M, KC);
        if (att == 0) {
            k_sgemm0<<<dim3(16, 16, 4), 256, 0, stream>>>(qb, kvb, nq, nk, S);
        } else {
            int nsplit = KC / 16, nslots = nsplit * 4;
            k_sgemm_split<<<dim3(15, nsplit, 4), 256, 0, stream>>>(qb, kvb, Spart, att, nslots);
            k_sreduce<<<dim3(15, 4), 256, 0, stream>>>(Spart, nq, nk, S, M, nslots);
        }
        k_softmax<<<dim3(M, 4), 256, 0, stream>>>(S, Pb, M);
        if (att == 0) {
            k_ogemm0<<<dim3(16, 25, 4), 256, 0, stream>>>(Pb, kvb, cat);
        } else {
            k_ogemm12<<<dim3(5, KC, 4), 256, 0, stream>>>(S, kvb, cat, att, M, KC);
        }
    }

    // 3. transpose to token-major
    k_transpose<<<dim3(32, 4, 100), 256, 0, stream>>>(cat, ct);

    // 4. LN + MLP + out projection
    k_lnstats<<<dim3(25600), 256, 0, stream>>>(ct, mu, rstd);
    k_mlp1<<<dim3(1600), 256, 0, stream>>>(ct, mu, rstd, ln_g, ln_b, W_m1, h1b);
    k_mlp2<<<dim3(1600), 256, 0, stream>>>(h1b, ct, W_m2, m2b);
    k_out <<<dim3(1600), 256, 0, stream>>>(m2b, W_ot, out);
}

// Round 4
// 497.810 us; speedup vs baseline: 6.0390x; 1.2327x over previous
//
#include <hip/hip_runtime.h>

#define NSP   25600   // 25*32*32 spatial elems per (b, channel)
#define HWC   1024    // 32*32

typedef __attribute__((ext_vector_type(8))) short bf8;   // 8 bf16 = 4 VGPRs
typedef __attribute__((ext_vector_type(4))) float f4;    // MFMA C/D frag
#define MFMA(a,b,c) __builtin_amdgcn_mfma_f32_16x16x32_bf16(a, b, c, 0, 0, 0)
typedef unsigned short u16;

__device__ __forceinline__ u16 f2b(float f) {
    union { float f; unsigned u; } v; v.f = f;
    unsigned r = v.u + 0x7fffu + ((v.u >> 16) & 1u);
    return (u16)(r >> 16);
}
__device__ __forceinline__ float b2f(u16 h) {
    union { unsigned u; float f; } v; v.u = ((unsigned)h) << 16;
    return v.f;
}

// Attention addressing (K re-chunked into 32-contig-float blocks; legal since
// fold K-order only needs consistency between q/k/v/unfold).
__device__ __forceinline__ long row_base(int att, int b, int m) {
    if (att == 0) { int cc = m >> 5, h = m & 31;   return ((long)(b*128 + cc))*NSP + h*32; }
    else if (att == 1) { int cc = m / 5, u = m - cc*5; return ((long)(b*128 + 32 + cc))*NSP + u*5120; }
    else { int h = m / 5, u = m - h*5;            return ((long)(b*128 + 64))*NSP + u*5120 + h*32; }
}
__device__ __forceinline__ long chunk_off(int att, int kc) {
    if (att == 0) return (long)kc * 1024;
    else if (att == 1) return (long)kc * 32;
    else { int cc = kc / 5, v = kc - cc*5; return (long)cc*NSP + v*1024; }
}

// ---------------- K1: token GEMMs (MFMA) -> bf16 q / kv --------------------
__global__ __launch_bounds__(256) void k_tokens(
        const float* __restrict__ x_hf, const float* __restrict__ x_lf,
        const float* __restrict__ W_in, const float* __restrict__ W_kv,
        u16* __restrict__ qb, u16* __restrict__ kvb) {
    // grid (400, 4, 2)
    int s0 = blockIdx.x * 64, b = blockIdx.y, which = blockIdx.z;
    const float* x  = which ? x_lf : x_hf;
    const float* Wt = which ? W_kv : W_in;
    u16* out = which ? kvb : qb;
    __shared__ u16 Axs[64 * 72];   // [token][c]
    __shared__ u16 Wl [128 * 72];  // [d][c]
    int tid = threadIdx.x;
    for (int idx = tid; idx < 8192; idx += 256) {      // W transpose-stage
        int c = idx >> 7, dd = idx & 127;
        Wl[dd * 72 + c] = f2b(Wt[idx]);
    }
    for (int idx = tid; idx < 4096; idx += 256) {      // x transpose-stage
        int c = idx >> 6, s = idx & 63;
        Axs[s * 72 + c] = f2b(x[(long)(b * 64 + c) * NSP + s0 + s]);
    }
    __syncthreads();
    int w = tid >> 6, l = tid & 63, quad = l >> 4, col = l & 15;
    f4 z = {0.f, 0.f, 0.f, 0.f};
    f4 acc[8]; for (int i = 0; i < 8; ++i) acc[i] = z;
#pragma unroll
    for (int kc = 0; kc < 2; ++kc) {
        bf8 a = *(bf8*)&Axs[(w * 16 + col) * 72 + kc * 32 + quad * 8];
#pragma unroll
        for (int nt = 0; nt < 8; ++nt) {
            bf8 bb = *(bf8*)&Wl[(nt * 16 + col) * 72 + kc * 32 + quad * 8];
            acc[nt] = MFMA(a, bb, acc[nt]);
        }
    }
#pragma unroll
    for (int nt = 0; nt < 8; ++nt) {
        int d = nt * 16 + col;
        long base = ((long)(b * 128 + d)) * NSP + s0 + w * 16 + quad * 4;
        ushort4 pk;
        pk.x = f2b(acc[nt][0]); pk.y = f2b(acc[nt][1]);
        pk.z = f2b(acc[nt][2]); pk.w = f2b(acc[nt][3]);
        *(ushort4*)(out + base) = pk;
    }
}

// ---------------- K2: row L2 norms (bf16 src) ------------------------------
__global__ __launch_bounds__(256) void k_norms(
        const u16* __restrict__ src, float* __restrict__ dst,
        int att, int M, int KC) {
    int m = blockIdx.x, b = blockIdx.y;
    long base = row_base(att, b, m);
    float s = 0.f;
    int K = KC * 32;
    for (int k = threadIdx.x; k < K; k += 256) {
        float v = b2f(src[base + chunk_off(att, k >> 5) + (k & 31)]);
        s += v * v;
    }
    __shared__ float red[256];
    red[threadIdx.x] = s; __syncthreads();
    for (int w = 128; w >= 1; w >>= 1) {
        if (threadIdx.x < w) red[threadIdx.x] += red[threadIdx.x + w];
        __syncthreads();
    }
    if (threadIdx.x == 0) dst[b * M + m] = fmaxf(sqrtf(red[0]), 1e-12f);
}

// ---------------- K3a: att0 S-GEMM (MFMA, 64x64 tile) ----------------------
__global__ __launch_bounds__(256) void k_sgemm0(
        const u16* __restrict__ qb, const u16* __restrict__ kvb,
        const float* __restrict__ nq, const float* __restrict__ nk,
        float* __restrict__ S) {
    // grid (16,16,4)
    if (blockIdx.y > blockIdx.x) return;
    int mt = blockIdx.x * 64, nt = blockIdx.y * 64, b = blockIdx.z;
    __shared__ u16 Qs[64 * 40], Ks[64 * 40];
    int tid = threadIdx.x, w = tid >> 6, l = tid & 63, quad = l >> 4, col = l & 15;
    int srow = tid >> 2, g = tid & 3;
    f4 z = {0.f, 0.f, 0.f, 0.f};
    f4 acc[4]; for (int i = 0; i < 4; ++i) acc[i] = z;
    for (int kc = 0; kc < 25; ++kc) {
        long co = (long)kc * 1024;
        {
            int m = mt + srow;
            *(bf8*)&Qs[srow * 40 + g * 8] =
                *(const bf8*)(qb + ((long)(b*128 + (m >> 5)))*NSP + (m & 31)*32 + co + g*8);
            int n = nt + srow;
            *(bf8*)&Ks[srow * 40 + g * 8] =
                *(const bf8*)(kvb + ((long)(b*128 + (n >> 5)))*NSP + (n & 31)*32 + co + g*8);
        }
        __syncthreads();
        bf8 a = *(bf8*)&Qs[(w * 16 + col) * 40 + quad * 8];
#pragma unroll
        for (int t2 = 0; t2 < 4; ++t2) {
            bf8 bb = *(bf8*)&Ks[(t2 * 16 + col) * 40 + quad * 8];
            acc[t2] = MFMA(a, bb, acc[t2]);
        }
        __syncthreads();
    }
#pragma unroll
    for (int t2 = 0; t2 < 4; ++t2)
#pragma unroll
        for (int r = 0; r < 4; ++r) {
            int m = mt + w * 16 + quad * 4 + r, n = nt + t2 * 16 + col;
            float v = (n <= m) ? acc[t2][r] / (nq[b*1024 + m] * nk[b*1024 + n]) : 0.f;
            S[((long)b * 1024 + m) * 1024 + n] = v;
        }
}

// ---------------- K3b: att1/2 split-K S-GEMM (MFMA + in-block reduce) ------
__global__ __launch_bounds__(256) void k_sgemm_split(
        const u16* __restrict__ qb, const u16* __restrict__ kvb,
        float* __restrict__ Spart, int att, int nsplit) {
    // grid (15, nsplit, 4); block 256 = 4 waves; 16 chunks/block (4/wave)
    int t = blockIdx.x, split = blockIdx.y, b = blockIdx.z;
    int i = 0;
    while (t >= (i + 1) * (i + 2) / 2) ++i;
    int j = t - i * (i + 1) / 2;
    int mt = i * 32, nt = j * 32;
    int tid = threadIdx.x, w = tid >> 6, l = tid & 63, quad = l >> 4, col = l & 15;
    long rm0 = row_base(att, b, mt + col),      rm1 = row_base(att, b, mt + 16 + col);
    long rn0 = row_base(att, b, nt + col),      rn1 = row_base(att, b, nt + 16 + col);
    int ko = quad * 8;
    f4 z = {0.f, 0.f, 0.f, 0.f};
    f4 a00 = z, a01 = z, a10 = z, a11 = z;
#pragma unroll
    for (int s = 0; s < 4; ++s) {
        int kc = split * 16 + w * 4 + s;
        long co = chunk_off(att, kc);
        bf8 qa0 = *(const bf8*)(qb + rm0 + co + ko);
        bf8 qa1 = *(const bf8*)(qb + rm1 + co + ko);
        bf8 kb0 = *(const bf8*)(kvb + rn0 + co + ko);
        bf8 kb1 = *(const bf8*)(kvb + rn1 + co + ko);
        a00 = MFMA(qa0, kb0, a00); a01 = MFMA(qa0, kb1, a01);
        a10 = MFMA(qa1, kb0, a10); a11 = MFMA(qa1, kb1, a11);
    }
    // each wave holds a full 32x32 partial -> reduce across waves in LDS
    __shared__ float red[4 * 1024];
    float* my = red + w * 1024;
#pragma unroll
    for (int r = 0; r < 4; ++r) {
        my[(quad * 4 + r) * 32 + col]            = a00[r];
        my[(quad * 4 + r) * 32 + 16 + col]       = a01[r];
        my[(16 + quad * 4 + r) * 32 + col]       = a10[r];
        my[(16 + quad * 4 + r) * 32 + 16 + col]  = a11[r];
    }
    __syncthreads();
    float* dst = Spart + ((long)((b * 15 + t) * nsplit + split)) * 1024;
    for (int e = tid; e < 1024; e += 256)
        dst[e] = red[e] + red[1024 + e] + red[2048 + e] + red[3072 + e];
}

// ---------------- K4a: att0 softmax (reads fp32 S, writes bf16 P only) -----
__global__ __launch_bounds__(256) void k_softmax0(
        const float* __restrict__ S, u16* __restrict__ Pb, int M) {
    int m = blockIdx.x, b = blockIdx.y;
    const float* row = S + ((long)b * M + m) * M;
    u16* pr = Pb + ((long)b * M + m) * M;
    int len = m + 1;
    __shared__ float red[256];
    float mx = -1e30f;
    for (int i = threadIdx.x; i < len; i += 256) mx = fmaxf(mx, row[i]);
    red[threadIdx.x] = mx; __syncthreads();
    for (int w = 128; w >= 1; w >>= 1) {
        if (threadIdx.x < w) red[threadIdx.x] = fmaxf(red[threadIdx.x], red[threadIdx.x + w]);
        __syncthreads();
    }
    mx = red[0]; __syncthreads();
    float sum = 0.f;
    for (int i = threadIdx.x; i < len; i += 256) sum += expf(row[i] - mx);
    red[threadIdx.x] = sum; __syncthreads();
    for (int w = 128; w >= 1; w >>= 1) {
        if (threadIdx.x < w) red[threadIdx.x] += red[threadIdx.x + w];
        __syncthreads();
    }
    float inv = 1.f / red[0];
    for (int i = threadIdx.x; i < len; i += 256) pr[i] = f2b(expf(row[i] - mx) * inv);
    for (int i = len + threadIdx.x; i < M; i += 256) pr[i] = 0;
}

// ---------------- K4b: att1/2 fused reduce+norm+mask+softmax ---------------
__global__ __launch_bounds__(256) void k_softmax12(
        const float* __restrict__ Spart, const float* __restrict__ nq,
        const float* __restrict__ nk, float* __restrict__ S,
        int M, int nsplit) {
    // grid (M, 4); one column per thread (M=160 <= 256)
    int m = blockIdx.x, b = blockIdx.y;
    int i = m >> 5, ro = (m & 31) * 32;
    int n = threadIdx.x;
    bool act = (n <= m) && (n < M);
    float myv = 0.f;
    if (act) {
        int t = i * (i + 1) / 2 + (n >> 5);
        const float* src = Spart + ((long)((b * 15 + t) * nsplit)) * 1024 + ro + (n & 31);
        float s = 0.f;
        for (int sp = 0; sp < nsplit; ++sp) s += src[(long)sp * 1024];
        myv = s / (nq[b * M + m] * nk[b * M + n]);
    }
    __shared__ float red[256];
    red[threadIdx.x] = act ? myv : -1e30f; __syncthreads();
    for (int w = 128; w >= 1; w >>= 1) {
        if (threadIdx.x < w) red[threadIdx.x] = fmaxf(red[threadIdx.x], red[threadIdx.x + w]);
        __syncthreads();
    }
    float mx = red[0]; __syncthreads();
    float e = act ? expf(myv - mx) : 0.f;
    red[threadIdx.x] = e; __syncthreads();
    for (int w = 128; w >= 1; w >>= 1) {
        if (threadIdx.x < w) red[threadIdx.x] += red[threadIdx.x + w];
        __syncthreads();
    }
    float inv = 1.f / red[0];
    if (n < M) S[((long)b * M + m) * M + n] = e * inv;
}

// ---------------- K5a: att0 O-GEMM (MFMA) + residual -----------------------
__global__ __launch_bounds__(256) void k_ogemm0(
        const u16* __restrict__ Pb, const u16* __restrict__ kvb,
        float* __restrict__ cat) {
    // grid (16, 25, 4): 64 q-rows x one 32-wide feature chunk
    int mt = blockIdx.x * 64, kc = blockIdx.y, b = blockIdx.z;
    long co = (long)kc * 1024;
    __shared__ u16 Ps[64 * 40], Vt[32 * 40];
    int tid = threadIdx.x, w = tid >> 6, l = tid & 63, quad = l >> 4, col = l & 15;
    f4 z = {0.f, 0.f, 0.f, 0.f};
    f4 acc[2]; acc[0] = z; acc[1] = z;
    int nchunks = (mt >> 5) + 2;
    for (int nt2 = 0; nt2 < nchunks; ++nt2) {
        *(bf8*)&Ps[(tid >> 2) * 40 + (tid & 3) * 8] =
            *(const bf8*)(Pb + ((long)b * 1024 + mt + (tid >> 2)) * 1024 + nt2 * 32 + (tid & 3) * 8);
        {
            int p = nt2 * 32 + (tid >> 3), pl = tid >> 3, f = (tid & 7) * 4;
            long rb = ((long)(b * 128 + (p >> 5))) * NSP + (p & 31) * 32 + co;
            ushort4 e = *(const ushort4*)(kvb + rb + f);
            Vt[f * 40 + pl] = e.x; Vt[(f + 1) * 40 + pl] = e.y;
            Vt[(f + 2) * 40 + pl] = e.z; Vt[(f + 3) * 40 + pl] = e.w;
        }
        __syncthreads();
        bf8 a = *(bf8*)&Ps[(w * 16 + col) * 40 + quad * 8];
#pragma unroll
        for (int t2 = 0; t2 < 2; ++t2) {
            bf8 bb = *(bf8*)&Vt[(t2 * 16 + col) * 40 + quad * 8];
            acc[t2] = MFMA(a, bb, acc[t2]);
        }
        __syncthreads();
    }
#pragma unroll
    for (int t2 = 0; t2 < 2; ++t2)
#pragma unroll
        for (int r = 0; r < 4; ++r) {
            int m = mt + w * 16 + quad * 4 + r, f = t2 * 16 + col;
            long adr = ((long)(b * 128 + (m >> 5))) * NSP + (m & 31) * 32 + co + f;
            cat[adr] = acc[t2][r] + b2f(kvb[adr]);
        }
}

// ---------------- K5b: att1/2 O-GEMM (fp32, bf16 V) ------------------------
__global__ __launch_bounds__(256) void k_ogemm12(
        const float* __restrict__ P, const u16* __restrict__ kvb,
        float* __restrict__ cat, int att, int M, int KC) {
    int mt = blockIdx.x * 32, kc = blockIdx.y, b = blockIdx.z;
    long co = chunk_off(att, kc);
    __shared__ float Pa[32][33], Va[32][33];
    float acc[2][2] = {};
    int tx = threadIdx.x & 15, ty = threadIdx.x >> 4;
    int tid = threadIdx.x, lr = tid >> 5, lk = tid & 31;
    int nmax = mt + 32; if (nmax > M) nmax = M;
    for (int nt = 0; nt < nmax; nt += 32) {
#pragma unroll
        for (int r = 0; r < 4; ++r) {
            int row = lr + r * 8;
            Pa[row][lk] = P[((long)b * M + mt + row) * M + nt + lk];
            Va[row][lk] = b2f(kvb[row_base(att, b, nt + row) + co + lk]);
        }
        __syncthreads();
#pragma unroll
        for (int kk = 0; kk < 32; ++kk) {
            float a0 = Pa[ty][kk], a1 = Pa[ty + 16][kk];
            float b0 = Va[kk][tx], b1 = Va[kk][tx + 16];
            acc[0][0] += a0 * b0; acc[0][1] += a0 * b1;
            acc[1][0] += a1 * b0; acc[1][1] += a1 * b1;
        }
        __syncthreads();
    }
#pragma unroll
    for (int i = 0; i < 2; ++i)
#pragma unroll
        for (int j = 0; j < 2; ++j) {
            int m = mt + ty + i * 16, k = tx + j * 16;
            long adr = row_base(att, b, m) + co + k;
            cat[adr] = acc[i][j] + b2f(kvb[adr]);
        }
}

// ---------------- K6: transpose cat (b,d,s) -> ct (token, d) ---------------
__global__ __launch_bounds__(256) void k_transpose(
        const float* __restrict__ cat, float* __restrict__ ct) {
    __shared__ float t[32][33];
    int hwt = blockIdx.x * 32, dt = blockIdx.y * 32, bn = blockIdx.z;
    int b = bn / 25, uv = bn - b * 25;
    const float* src = cat + (long)b * 128 * NSP + uv * HWC;
    int tx = threadIdx.x & 31, ty = threadIdx.x >> 5;
    for (int r = ty; r < 32; r += 8)
        t[r][tx] = src[(long)(dt + r) * NSP + hwt + tx];
    __syncthreads();
    float* dst = ct + (long)bn * HWC * 128;
    for (int r = ty; r < 32; r += 8)
        dst[(long)(hwt + r) * 128 + dt + tx] = t[tx][r];
}

// ---------------- K7: LayerNorm stats --------------------------------------
__global__ __launch_bounds__(256) void k_lnstats(
        const float* __restrict__ ct, float* __restrict__ mu, float* __restrict__ rstd) {
    int t = blockIdx.x * 4 + (threadIdx.x >> 6);
    int lane = threadIdx.x & 63;
    const float* row = ct + (long)t * 128;
    float v0 = row[lane], v1 = row[lane + 64];
    float s = v0 + v1, s2 = v0 * v0 + v1 * v1;
    for (int o = 32; o >= 1; o >>= 1) { s += __shfl_down(s, o); s2 += __shfl_down(s2, o); }
    if (lane == 0) {
        float m = s * (1.f / 128.f);
        float var = s2 * (1.f / 128.f) - m * m;
        mu[t] = m; rstd[t] = rsqrtf(var + 1e-5f);
    }
}

// ---------------- K8: h1 = relu(LN(ct) @ W1) (MFMA) ------------------------
__global__ __launch_bounds__(256) void k_mlp1(
        const float* __restrict__ ct, const float* __restrict__ mu,
        const float* __restrict__ rstd, const float* __restrict__ g,
        const float* __restrict__ be, const float* __restrict__ W1,
        u16* __restrict__ h1b) {
    int tt = blockIdx.x * 64, tid = threadIdx.x;
    __shared__ u16 As[64 * 136], Wt[128 * 136];
    for (int idx = tid; idx < 16384; idx += 256) {
        int k = idx >> 7, n = idx & 127;
        Wt[n * 136 + k] = f2b(W1[idx]);
    }
    for (int idx = tid; idx < 8192; idx += 256) {
        int row = idx >> 7, k = idx & 127, t = tt + row;
        float v = (ct[(long)t * 128 + k] - mu[t]) * rstd[t] * g[k] + be[k];
        As[row * 136 + k] = f2b(v);
    }
    __syncthreads();
    int w = tid >> 6, l = tid & 63, quad = l >> 4, col = l & 15;
    f4 z = {0.f, 0.f, 0.f, 0.f};
    f4 acc[8]; for (int i = 0; i < 8; ++i) acc[i] = z;
#pragma unroll
    for (int kc = 0; kc < 4; ++kc) {
        bf8 a = *(bf8*)&As[(w * 16 + col) * 136 + kc * 32 + quad * 8];
#pragma unroll
        for (int nt = 0; nt < 8; ++nt) {
            bf8 bb = *(bf8*)&Wt[(nt * 16 + col) * 136 + kc * 32 + quad * 8];
            acc[nt] = MFMA(a, bb, acc[nt]);
        }
    }
#pragma unroll
    for (int nt = 0; nt < 8; ++nt)
#pragma unroll
        for (int r = 0; r < 4; ++r) {
            int t = tt + w * 16 + quad * 4 + r, n = nt * 16 + col;
            h1b[(long)t * 128 + n] = f2b(fmaxf(acc[nt][r], 0.f));
        }
}

// ---------------- K9: m2 = h1 @ W2 + ct (MFMA) -----------------------------
__global__ __launch_bounds__(256) void k_mlp2(
        const u16* __restrict__ h1b, const float* __restrict__ ct,
        const float* __restrict__ W2, u16* __restrict__ m2b) {
    int tt = blockIdx.x * 64, tid = threadIdx.x;
    __shared__ u16 As[64 * 136], Wt[128 * 136];
    for (int idx = tid; idx < 16384; idx += 256) {
        int k = idx >> 7, n = idx & 127;
        Wt[n * 136 + k] = f2b(W2[idx]);
    }
    for (int idx = tid; idx < 2048; idx += 256) {
        int row = idx >> 5, kg = (idx & 31) * 4;
        *(ushort4*)&As[row * 136 + kg] = *(const ushort4*)(h1b + (long)(tt + row) * 128 + kg);
    }
    __syncthreads();
    int w = tid >> 6, l = tid & 63, quad = l >> 4, col = l & 15;
    f4 z = {0.f, 0.f, 0.f, 0.f};
    f4 acc[8]; for (int i = 0; i < 8; ++i) acc[i] = z;
#pragma unroll
    for (int kc = 0; kc < 4; ++kc) {
        bf8 a = *(bf8*)&As[(w * 16 + col) * 136 + kc * 32 + quad * 8];
#pragma unroll
        for (int nt = 0; nt < 8; ++nt) {
            bf8 bb = *(bf8*)&Wt[(nt * 16 + col) * 136 + kc * 32 + quad * 8];
            acc[nt] = MFMA(a, bb, acc[nt]);
        }
    }
#pragma unroll
    for (int nt = 0; nt < 8; ++nt)
#pragma unroll
        for (int r = 0; r < 4; ++r) {
            int t = tt + w * 16 + quad * 4 + r, n = nt * 16 + col;
            m2b[(long)t * 128 + n] = f2b(acc[nt][r] + ct[(long)t * 128 + n]);
        }
}

// ---------------- K10: out = m2 @ W_out (MFMA), scatter --------------------
__global__ __launch_bounds__(256) void k_out(
        const u16* __restrict__ m2b, const float* __restrict__ Wo,
        float* __restrict__ out) {
    int tt = blockIdx.x * 64, tid = threadIdx.x;
    __shared__ u16 As[64 * 136], Wt[64 * 136];
    for (int idx = tid; idx < 8192; idx += 256) {
        int k = idx >> 6, o = idx & 63;
        Wt[o * 136 + k] = f2b(Wo[idx]);
    }
    for (int idx = tid; idx < 2048; idx += 256) {
        int row = idx >> 5, kg = (idx & 31) * 4;
        *(ushort4*)&As[row * 136 + kg] = *(const ushort4*)(m2b + (long)(tt + row) * 128 + kg);
    }
    __syncthreads();
    int w = tid >> 6, l = tid & 63, quad = l >> 4, col = l & 15;
    f4 z = {0.f, 0.f, 0.f, 0.f};
    f4 acc[4]; for (int i = 0; i < 4; ++i) acc[i] = z;
#pragma unroll
    for (int kc = 0; kc < 4; ++kc) {
        bf8 a = *(bf8*)&As[(w * 16 + col) * 136 + kc * 32 + quad * 8];
#pragma unroll
        for (int nt = 0; nt < 4; ++nt) {
            bf8 bb = *(bf8*)&Wt[(nt * 16 + col) * 136 + kc * 32 + quad * 8];
            acc[nt] = MFMA(a, bb, acc[nt]);
        }
    }
    int t0 = tt + w * 16 + quad * 4;
    int bn = t0 >> 10, hw = t0 & 1023;
    int b = bn / 25, uv = bn - b * 25;
#pragma unroll
    for (int nt = 0; nt < 4; ++nt) {
        int o = nt * 16 + col;
        float4 pk = {acc[nt][0], acc[nt][1], acc[nt][2], acc[nt][3]};
        *(float4*)(out + ((long)((b * 64 + o) * 25 + uv)) * 1024 + hw) = pk;
    }
}

// ---------------- launch ---------------------------------------------------
extern "C" void kernel_launch(void* const* d_in, const int* in_sizes, int n_in,
                              void* d_out, int out_size, void* d_ws, size_t ws_size,
                              hipStream_t stream) {
    const float* x_lf = (const float*)d_in[0];
    const float* x_hf = (const float*)d_in[1];
    const float* W_in = (const float*)d_in[2];
    const float* W_kv = (const float*)d_in[3];
    const float* ln_g = (const float*)d_in[4];
    const float* ln_b = (const float*)d_in[5];
    const float* W_m1 = (const float*)d_in[6];
    const float* W_m2 = (const float*)d_in[7];
    const float* W_ot = (const float*)d_in[8];
    float* out = (float*)d_out;

    float* ws = (float*)d_ws;
    u16*   Pb    = (u16*)ws;                          // 4*1024*1024 bf16
    float* Spart = ws + 2097152;                      // <= 4*15*20*1024 fp32
    float* ct    = ws;                                // after attention
    float* cat   = ws + 13107200;                     // 13.1M fp32
    u16*   m2b   = (u16*)(ws + 13107200);             // after transpose (over cat)
    u16*   qb    = (u16*)(ws + 26214400);             // 13.1M bf16
    u16*   h1b   = (u16*)(ws + 26214400);             // after attention (over qb)
    u16*   kvb   = (u16*)(ws + 32768000);             // 13.1M bf16
    float* S     = ws + 39321600;                     // 4.19M fp32
    float* nq    = ws + 43515904;
    float* nk    = nq + 4096;
    float* mu    = nk + 4096;
    float* rstd  = mu + 102400;

    // 1. token GEMMs -> bf16 q/kv
    k_tokens<<<dim3(400, 4, 2), 256, 0, stream>>>(x_hf, x_lf, W_in, W_kv, qb, kvb);

    // 2. three attentions
    const int Ms[3]  = {1024, 160, 160};
    const int KCs[3] = {25, 160, 320};
    for (int att = 0; att < 3; ++att) {
        int M = Ms[att], KC = KCs[att];
        k_norms<<<dim3(M, 4), 256, 0, stream>>>(qb,  nq, att, M, KC);
        k_norms<<<dim3(M, 4), 256, 0, stream>>>(kvb, nk, att, M, KC);
        if (att == 0) {
            k_sgemm0<<<dim3(16, 16, 4), 256, 0, stream>>>(qb, kvb, nq, nk, S);
            k_softmax0<<<dim3(M, 4), 256, 0, stream>>>(S, Pb, M);
            k_ogemm0<<<dim3(16, 25, 4), 256, 0, stream>>>(Pb, kvb, cat);
        } else {
            int nsplit = KC / 16;                     // att1: 10, att2: 20
            k_sgemm_split<<<dim3(15, nsplit, 4), 256, 0, stream>>>(qb, kvb, Spart, att, nsplit);
            k_softmax12<<<dim3(M, 4), 256, 0, stream>>>(Spart, nq, nk, S, M, nsplit);
            k_ogemm12<<<dim3(5, KC, 4), 256, 0, stream>>>(S, kvb, cat, att, M, KC);
        }
    }

    // 3. transpose to token-major
    k_transpose<<<dim3(32, 4, 100), 256, 0, stream>>>(cat, ct);

    // 4. LN + MLP + out projection
    k_lnstats<<<dim3(25600), 256, 0, stream>>>(ct, mu, rstd);
    k_mlp1<<<dim3(1600), 256, 0, stream>>>(ct, mu, rstd, ln_g, ln_b, W_m1, h1b);
    k_mlp2<<<dim3(1600), 256, 0, stream>>>(h1b, ct, W_m2, m2b);
    k_out <<<dim3(1600), 256, 0, stream>>>(m2b, W_ot, out);
}

// Round 5
// 403.149 us; speedup vs baseline: 7.4569x; 1.2348x over previous
//
#include <hip/hip_runtime.h>

#define NSP   25600   // 25*32*32 spatial elems per (b, channel)
#define HWC   1024    // 32*32

typedef __attribute__((ext_vector_type(8))) short bf8;   // 8 bf16 = 4 VGPRs
typedef __attribute__((ext_vector_type(4))) float f4;    // MFMA C/D frag
#define MFMA(a,b,c) __builtin_amdgcn_mfma_f32_16x16x32_bf16(a, b, c, 0, 0, 0)
typedef unsigned short u16;

__device__ __forceinline__ u16 f2b(float f) {
    union { float f; unsigned u; } v; v.f = f;
    unsigned r = v.u + 0x7fffu + ((v.u >> 16) & 1u);
    return (u16)(r >> 16);
}
__device__ __forceinline__ float b2f(u16 h) {
    union { unsigned u; float f; } v; v.u = ((unsigned)h) << 16;
    return v.f;
}

// Attention addressing (K re-chunked into 32-contig-elem blocks; legal since
// fold K-order only needs consistency between q/k/v/unfold).
__device__ __forceinline__ long row_base(int att, int b, int m) {
    if (att == 0) { int cc = m >> 5, h = m & 31;   return ((long)(b*128 + cc))*NSP + h*32; }
    else if (att == 1) { int cc = m / 5, u = m - cc*5; return ((long)(b*128 + 32 + cc))*NSP + u*5120; }
    else { int h = m / 5, u = m - h*5;            return ((long)(b*128 + 64))*NSP + u*5120 + h*32; }
}
__device__ __forceinline__ long chunk_off(int att, int kc) {
    if (att == 0) return (long)kc * 1024;
    else if (att == 1) return (long)kc * 32;
    else { int cc = kc / 5, v = kc - cc*5; return (long)cc*NSP + v*1024; }
}

// ---------------- K1: token GEMMs (MFMA) -> bf16 q / kv --------------------
__global__ __launch_bounds__(256) void k_tokens(
        const float* __restrict__ x_hf, const float* __restrict__ x_lf,
        const float* __restrict__ W_in, const float* __restrict__ W_kv,
        u16* __restrict__ qb, u16* __restrict__ kvb) {
    // grid (400, 4, 2)
    int s0 = blockIdx.x * 64, b = blockIdx.y, which = blockIdx.z;
    const float* x  = which ? x_lf : x_hf;
    const float* Wt = which ? W_kv : W_in;
    u16* out = which ? kvb : qb;
    __shared__ u16 Axs[64 * 72];   // [token][c]
    __shared__ u16 Wl [128 * 72];  // [d][c]
    int tid = threadIdx.x;
    for (int idx = tid; idx < 8192; idx += 256) {      // W transpose-stage
        int c = idx >> 7, dd = idx & 127;
        Wl[dd * 72 + c] = f2b(Wt[idx]);
    }
    for (int idx = tid; idx < 4096; idx += 256) {      // x transpose-stage
        int c = idx >> 6, s = idx & 63;
        Axs[s * 72 + c] = f2b(x[(long)(b * 64 + c) * NSP + s0 + s]);
    }
    __syncthreads();
    int w = tid >> 6, l = tid & 63, quad = l >> 4, col = l & 15;
    f4 z = {0.f, 0.f, 0.f, 0.f};
    f4 acc[8]; for (int i = 0; i < 8; ++i) acc[i] = z;
#pragma unroll
    for (int kc = 0; kc < 2; ++kc) {
        bf8 a = *(bf8*)&Axs[(w * 16 + col) * 72 + kc * 32 + quad * 8];
#pragma unroll
        for (int nt = 0; nt < 8; ++nt) {
            bf8 bb = *(bf8*)&Wl[(nt * 16 + col) * 72 + kc * 32 + quad * 8];
            acc[nt] = MFMA(a, bb, acc[nt]);
        }
    }
#pragma unroll
    for (int nt = 0; nt < 8; ++nt) {
        int d = nt * 16 + col;
        long base = ((long)(b * 128 + d)) * NSP + s0 + w * 16 + quad * 4;
        ushort4 pk;
        pk.x = f2b(acc[nt][0]); pk.y = f2b(acc[nt][1]);
        pk.z = f2b(acc[nt][2]); pk.w = f2b(acc[nt][3]);
        *(ushort4*)(out + base) = pk;
    }
}

// ---------------- K2: row L2 norms (q and kv in one dispatch) --------------
__global__ __launch_bounds__(256) void k_norms2(
        const u16* __restrict__ qb, const u16* __restrict__ kvb,
        float* __restrict__ nq, float* __restrict__ nk,
        int att, int M, int KC) {
    // grid (M, 4, 2)
    int m = blockIdx.x, b = blockIdx.y, which = blockIdx.z;
    const u16* src = which ? kvb : qb;
    float* dst = which ? nk : nq;
    long base = row_base(att, b, m);
    float s = 0.f;
    int K = KC * 32;
    for (int k = threadIdx.x; k < K; k += 256) {
        float v = b2f(src[base + chunk_off(att, k >> 5) + (k & 31)]);
        s += v * v;
    }
    __shared__ float red[256];
    red[threadIdx.x] = s; __syncthreads();
    for (int w = 128; w >= 1; w >>= 1) {
        if (threadIdx.x < w) red[threadIdx.x] += red[threadIdx.x + w];
        __syncthreads();
    }
    if (threadIdx.x == 0) dst[b * M + m] = fmaxf(sqrtf(red[0]), 1e-12f);
}

// ---------------- K3a: att0 S-GEMM (MFMA, 64x64 tile) -> bf16 S ------------
__global__ __launch_bounds__(256) void k_sgemm0(
        const u16* __restrict__ qb, const u16* __restrict__ kvb,
        const float* __restrict__ nq, const float* __restrict__ nk,
        u16* __restrict__ Sb) {
    // grid (16,16,4)
    if (blockIdx.y > blockIdx.x) return;
    int mt = blockIdx.x * 64, nt = blockIdx.y * 64, b = blockIdx.z;
    __shared__ u16 Qs[64 * 40], Ks[64 * 40];
    int tid = threadIdx.x, w = tid >> 6, l = tid & 63, quad = l >> 4, col = l & 15;
    int srow = tid >> 2, g = tid & 3;
    f4 z = {0.f, 0.f, 0.f, 0.f};
    f4 acc[4]; for (int i = 0; i < 4; ++i) acc[i] = z;
    for (int kc = 0; kc < 25; ++kc) {
        long co = (long)kc * 1024;
        {
            int m = mt + srow;
            *(bf8*)&Qs[srow * 40 + g * 8] =
                *(const bf8*)(qb + ((long)(b*128 + (m >> 5)))*NSP + (m & 31)*32 + co + g*8);
            int n = nt + srow;
            *(bf8*)&Ks[srow * 40 + g * 8] =
                *(const bf8*)(kvb + ((long)(b*128 + (n >> 5)))*NSP + (n & 31)*32 + co + g*8);
        }
        __syncthreads();
        bf8 a = *(bf8*)&Qs[(w * 16 + col) * 40 + quad * 8];
#pragma unroll
        for (int t2 = 0; t2 < 4; ++t2) {
            bf8 bb = *(bf8*)&Ks[(t2 * 16 + col) * 40 + quad * 8];
            acc[t2] = MFMA(a, bb, acc[t2]);
        }
        __syncthreads();
    }
#pragma unroll
    for (int t2 = 0; t2 < 4; ++t2)
#pragma unroll
        for (int r = 0; r < 4; ++r) {
            int m = mt + w * 16 + quad * 4 + r, n = nt + t2 * 16 + col;
            float v = (n <= m) ? acc[t2][r] / (nq[b*1024 + m] * nk[b*1024 + n]) : 0.f;
            Sb[((long)b * 1024 + m) * 1024 + n] = f2b(v);
        }
}

// ---------------- K3b: att1/2 split-K S-GEMM (MFMA + in-block reduce) ------
__global__ __launch_bounds__(256) void k_sgemm_split(
        const u16* __restrict__ qb, const u16* __restrict__ kvb,
        float* __restrict__ Spart, int att, int nsplit) {
    // grid (15, nsplit, 4); block 256 = 4 waves; 16 chunks/block (4/wave)
    int t = blockIdx.x, split = blockIdx.y, b = blockIdx.z;
    int i = 0;
    while (t >= (i + 1) * (i + 2) / 2) ++i;
    int j = t - i * (i + 1) / 2;
    int mt = i * 32, nt = j * 32;
    int tid = threadIdx.x, w = tid >> 6, l = tid & 63, quad = l >> 4, col = l & 15;
    long rm0 = row_base(att, b, mt + col),      rm1 = row_base(att, b, mt + 16 + col);
    long rn0 = row_base(att, b, nt + col),      rn1 = row_base(att, b, nt + 16 + col);
    int ko = quad * 8;
    f4 z = {0.f, 0.f, 0.f, 0.f};
    f4 a00 = z, a01 = z, a10 = z, a11 = z;
#pragma unroll
    for (int s = 0; s < 4; ++s) {
        int kc = split * 16 + w * 4 + s;
        long co = chunk_off(att, kc);
        bf8 qa0 = *(const bf8*)(qb + rm0 + co + ko);
        bf8 qa1 = *(const bf8*)(qb + rm1 + co + ko);
        bf8 kb0 = *(const bf8*)(kvb + rn0 + co + ko);
        bf8 kb1 = *(const bf8*)(kvb + rn1 + co + ko);
        a00 = MFMA(qa0, kb0, a00); a01 = MFMA(qa0, kb1, a01);
        a10 = MFMA(qa1, kb0, a10); a11 = MFMA(qa1, kb1, a11);
    }
    __shared__ float red[4 * 1024];
    float* my = red + w * 1024;
#pragma unroll
    for (int r = 0; r < 4; ++r) {
        my[(quad * 4 + r) * 32 + col]            = a00[r];
        my[(quad * 4 + r) * 32 + 16 + col]       = a01[r];
        my[(16 + quad * 4 + r) * 32 + col]       = a10[r];
        my[(16 + quad * 4 + r) * 32 + 16 + col]  = a11[r];
    }
    __syncthreads();
    float* dst = Spart + ((long)((b * 15 + t) * nsplit + split)) * 1024;
    for (int e = tid; e < 1024; e += 256)
        dst[e] = red[e] + red[1024 + e] + red[2048 + e] + red[3072 + e];
}

// ---------------- K4a: att0 softmax (bf16 S -> bf16 P) ---------------------
__global__ __launch_bounds__(256) void k_softmax0(
        const u16* __restrict__ Sb, u16* __restrict__ Pb, int M) {
    int m = blockIdx.x, b = blockIdx.y;
    const u16* row = Sb + ((long)b * M + m) * M;
    u16* pr = Pb + ((long)b * M + m) * M;
    int len = m + 1;
    __shared__ float red[256];
    float mx = -1e30f;
    for (int i = threadIdx.x; i < len; i += 256) mx = fmaxf(mx, b2f(row[i]));
    red[threadIdx.x] = mx; __syncthreads();
    for (int w = 128; w >= 1; w >>= 1) {
        if (threadIdx.x < w) red[threadIdx.x] = fmaxf(red[threadIdx.x], red[threadIdx.x + w]);
        __syncthreads();
    }
    mx = red[0]; __syncthreads();
    float sum = 0.f;
    for (int i = threadIdx.x; i < len; i += 256) sum += expf(b2f(row[i]) - mx);
    red[threadIdx.x] = sum; __syncthreads();
    for (int w = 128; w >= 1; w >>= 1) {
        if (threadIdx.x < w) red[threadIdx.x] += red[threadIdx.x + w];
        __syncthreads();
    }
    float inv = 1.f / red[0];
    for (int i = threadIdx.x; i < len; i += 256) pr[i] = f2b(expf(b2f(row[i]) - mx) * inv);
    for (int i = len + threadIdx.x; i < M; i += 256) pr[i] = 0;
}

// ---------------- K4b: att1/2 fused reduce+norm+mask+softmax -> bf16 P -----
__global__ __launch_bounds__(256) void k_softmax12(
        const float* __restrict__ Spart, const float* __restrict__ nq,
        const float* __restrict__ nk, u16* __restrict__ Pb12,
        int M, int nsplit) {
    // grid (M, 4); one column per thread (M=160 <= 256)
    int m = blockIdx.x, b = blockIdx.y;
    int i = m >> 5, ro = (m & 31) * 32;
    int n = threadIdx.x;
    bool act = (n <= m) && (n < M);
    float myv = 0.f;
    if (act) {
        int t = i * (i + 1) / 2 + (n >> 5);
        const float* src = Spart + ((long)((b * 15 + t) * nsplit)) * 1024 + ro + (n & 31);
        float s = 0.f;
        for (int sp = 0; sp < nsplit; ++sp) s += src[(long)sp * 1024];
        myv = s / (nq[b * M + m] * nk[b * M + n]);
    }
    __shared__ float red[256];
    red[threadIdx.x] = act ? myv : -1e30f; __syncthreads();
    for (int w = 128; w >= 1; w >>= 1) {
        if (threadIdx.x < w) red[threadIdx.x] = fmaxf(red[threadIdx.x], red[threadIdx.x + w]);
        __syncthreads();
    }
    float mx = red[0]; __syncthreads();
    float e = act ? expf(myv - mx) : 0.f;
    red[threadIdx.x] = e; __syncthreads();
    for (int w = 128; w >= 1; w >>= 1) {
        if (threadIdx.x < w) red[threadIdx.x] += red[threadIdx.x + w];
        __syncthreads();
    }
    float inv = 1.f / red[0];
    if (n < M) Pb12[((long)b * M + m) * M + n] = f2b(e * inv);
}

// ---------------- K5a: att0 O-GEMM (MFMA) + residual -> bf16 cat -----------
__global__ __launch_bounds__(256) void k_ogemm0(
        const u16* __restrict__ Pb, const u16* __restrict__ kvb,
        u16* __restrict__ catb) {
    // grid (16, 25, 4): 64 q-rows x one 32-wide feature chunk
    int mt = blockIdx.x * 64, kc = blockIdx.y, b = blockIdx.z;
    long co = (long)kc * 1024;
    __shared__ u16 Ps[64 * 40], Vt[32 * 40];
    int tid = threadIdx.x, w = tid >> 6, l = tid & 63, quad = l >> 4, col = l & 15;
    f4 z = {0.f, 0.f, 0.f, 0.f};
    f4 acc[2]; acc[0] = z; acc[1] = z;
    int nchunks = (mt >> 5) + 2;
    for (int nt2 = 0; nt2 < nchunks; ++nt2) {
        *(bf8*)&Ps[(tid >> 2) * 40 + (tid & 3) * 8] =
            *(const bf8*)(Pb + ((long)b * 1024 + mt + (tid >> 2)) * 1024 + nt2 * 32 + (tid & 3) * 8);
        {
            int p = nt2 * 32 + (tid >> 3), pl = tid >> 3, f = (tid & 7) * 4;
            long rb = ((long)(b * 128 + (p >> 5))) * NSP + (p & 31) * 32 + co;
            ushort4 e = *(const ushort4*)(kvb + rb + f);
            Vt[f * 40 + pl] = e.x; Vt[(f + 1) * 40 + pl] = e.y;
            Vt[(f + 2) * 40 + pl] = e.z; Vt[(f + 3) * 40 + pl] = e.w;
        }
        __syncthreads();
        bf8 a = *(bf8*)&Ps[(w * 16 + col) * 40 + quad * 8];
#pragma unroll
        for (int t2 = 0; t2 < 2; ++t2) {
            bf8 bb = *(bf8*)&Vt[(t2 * 16 + col) * 40 + quad * 8];
            acc[t2] = MFMA(a, bb, acc[t2]);
        }
        __syncthreads();
    }
#pragma unroll
    for (int t2 = 0; t2 < 2; ++t2)
#pragma unroll
        for (int r = 0; r < 4; ++r) {
            int m = mt + w * 16 + quad * 4 + r, f = t2 * 16 + col;
            long adr = ((long)(b * 128 + (m >> 5))) * NSP + (m & 31) * 32 + co + f;
            catb[adr] = f2b(acc[t2][r] + b2f(kvb[adr]));
        }
}

// ---------------- K5b: att1/2 O-GEMM (MFMA) + residual -> bf16 cat ---------
__global__ __launch_bounds__(256) void k_ogemm12m(
        const u16* __restrict__ Pb12, const u16* __restrict__ kvb,
        u16* __restrict__ catb, int att, int KC) {
    // grid (5, KC, 4): 32 m-rows x one 32-wide feature chunk
    int it = blockIdx.x, kc = blockIdx.y, b = blockIdx.z;
    int mt = it * 32;
    long co = chunk_off(att, kc);
    __shared__ u16 Ps[32 * 40], Vt[32 * 40];
    int tid = threadIdx.x, w = tid >> 6, l = tid & 63, quad = l >> 4, col = l & 15;
    int mh = w & 1, fh = w >> 1;
    f4 acc = {0.f, 0.f, 0.f, 0.f};
    for (int nt2 = 0; nt2 <= it; ++nt2) {
        {
            int row = tid >> 3, c4 = (tid & 7) * 4;
            *(ushort4*)&Ps[row * 40 + c4] =
                *(const ushort4*)(Pb12 + ((long)(b * 160 + mt + row)) * 160 + nt2 * 32 + c4);
        }
        {
            int pl = tid >> 3, f = (tid & 7) * 4;
            long rb = row_base(att, b, nt2 * 32 + pl) + co;
            ushort4 e = *(const ushort4*)(kvb + rb + f);
            Vt[f * 40 + pl] = e.x; Vt[(f + 1) * 40 + pl] = e.y;
            Vt[(f + 2) * 40 + pl] = e.z; Vt[(f + 3) * 40 + pl] = e.w;
        }
        __syncthreads();
        bf8 a  = *(bf8*)&Ps[(mh * 16 + col) * 40 + quad * 8];
        bf8 bb = *(bf8*)&Vt[(fh * 16 + col) * 40 + quad * 8];
        acc = MFMA(a, bb, acc);
        __syncthreads();
    }
#pragma unroll
    for (int r = 0; r < 4; ++r) {
        int m = mt + mh * 16 + quad * 4 + r, f = fh * 16 + col;
        long adr = row_base(att, b, m) + co + f;
        catb[adr] = f2b(acc[r] + b2f(kvb[adr]));
    }
}

// ---------------- K6: transpose cat (b,d,s) -> ct (token, d), bf16 ---------
__global__ __launch_bounds__(256) void k_transpose(
        const u16* __restrict__ catb, u16* __restrict__ ctb) {
    // grid (16, 4, 100): 64 hw x 32 d tile
    __shared__ u16 t[64 * 40];
    int hwt = blockIdx.x * 64, dt = blockIdx.y * 32, bn = blockIdx.z;
    int b = bn / 25, uv = bn - b * 25;
    const u16* src = catb + (long)b * 128 * NSP + (long)uv * HWC;
    int tid = threadIdx.x;
    {
        int r = tid >> 3, c8 = (tid & 7) * 8;
        bf8 v = *(const bf8*)(src + (long)(dt + r) * NSP + hwt + c8);
#pragma unroll
        for (int j = 0; j < 8; ++j) t[(c8 + j) * 40 + r] = ((u16*)&v)[j];
    }
    __syncthreads();
    {
        int hw = tid >> 2, d8 = (tid & 3) * 8;
        *(bf8*)(ctb + ((long)bn * HWC + hwt + hw) * 128 + dt + d8) =
            *(bf8*)&t[hw * 40 + d8];
    }
}

// ---------------- K7: LayerNorm stats (bf16 ct) ----------------------------
__global__ __launch_bounds__(256) void k_lnstats(
        const u16* __restrict__ ctb, float* __restrict__ mu, float* __restrict__ rstd) {
    int t = blockIdx.x * 4 + (threadIdx.x >> 6);
    int lane = threadIdx.x & 63;
    const u16* row = ctb + (long)t * 128;
    float v0 = b2f(row[lane]), v1 = b2f(row[lane + 64]);
    float s = v0 + v1, s2 = v0 * v0 + v1 * v1;
    for (int o = 32; o >= 1; o >>= 1) { s += __shfl_down(s, o); s2 += __shfl_down(s2, o); }
    if (lane == 0) {
        float m = s * (1.f / 128.f);
        float var = s2 * (1.f / 128.f) - m * m;
        mu[t] = m; rstd[t] = rsqrtf(var + 1e-5f);
    }
}

// ---------------- K8: h1 = relu(LN(ct) @ W1) (MFMA) ------------------------
__global__ __launch_bounds__(256) void k_mlp1(
        const u16* __restrict__ ctb, const float* __restrict__ mu,
        const float* __restrict__ rstd, const float* __restrict__ g,
        const float* __restrict__ be, const float* __restrict__ W1,
        u16* __restrict__ h1b) {
    int tt = blockIdx.x * 64, tid = threadIdx.x;
    __shared__ u16 As[64 * 136], Wt[128 * 136];
    for (int idx = tid; idx < 16384; idx += 256) {
        int k = idx >> 7, n = idx & 127;
        Wt[n * 136 + k] = f2b(W1[idx]);
    }
    for (int idx = tid; idx < 8192; idx += 256) {
        int row = idx >> 7, k = idx & 127, t = tt + row;
        float v = (b2f(ctb[(long)t * 128 + k]) - mu[t]) * rstd[t] * g[k] + be[k];
        As[row * 136 + k] = f2b(v);
    }
    __syncthreads();
    int w = tid >> 6, l = tid & 63, quad = l >> 4, col = l & 15;
    f4 z = {0.f, 0.f, 0.f, 0.f};
    f4 acc[8]; for (int i = 0; i < 8; ++i) acc[i] = z;
#pragma unroll
    for (int kc = 0; kc < 4; ++kc) {
        bf8 a = *(bf8*)&As[(w * 16 + col) * 136 + kc * 32 + quad * 8];
#pragma unroll
        for (int nt = 0; nt < 8; ++nt) {
            bf8 bb = *(bf8*)&Wt[(nt * 16 + col) * 136 + kc * 32 + quad * 8];
            acc[nt] = MFMA(a, bb, acc[nt]);
        }
    }
#pragma unroll
    for (int nt = 0; nt < 8; ++nt)
#pragma unroll
        for (int r = 0; r < 4; ++r) {
            int t = tt + w * 16 + quad * 4 + r, n = nt * 16 + col;
            h1b[(long)t * 128 + n] = f2b(fmaxf(acc[nt][r], 0.f));
        }
}

// ---------------- K9: m2 = h1 @ W2 + ct (MFMA) -----------------------------
__global__ __launch_bounds__(256) void k_mlp2(
        const u16* __restrict__ h1b, const u16* __restrict__ ctb,
        const float* __restrict__ W2, u16* __restrict__ m2b) {
    int tt = blockIdx.x * 64, tid = threadIdx.x;
    __shared__ u16 As[64 * 136], Wt[128 * 136];
    for (int idx = tid; idx < 16384; idx += 256) {
        int k = idx >> 7, n = idx & 127;
        Wt[n * 136 + k] = f2b(W2[idx]);
    }
    for (int idx = tid; idx < 2048; idx += 256) {
        int row = idx >> 5, kg = (idx & 31) * 4;
        *(ushort4*)&As[row * 136 + kg] = *(const ushort4*)(h1b + (long)(tt + row) * 128 + kg);
    }
    __syncthreads();
    int w = tid >> 6, l = tid & 63, quad = l >> 4, col = l & 15;
    f4 z = {0.f, 0.f, 0.f, 0.f};
    f4 acc[8]; for (int i = 0; i < 8; ++i) acc[i] = z;
#pragma unroll
    for (int kc = 0; kc < 4; ++kc) {
        bf8 a = *(bf8*)&As[(w * 16 + col) * 136 + kc * 32 + quad * 8];
#pragma unroll
        for (int nt = 0; nt < 8; ++nt) {
            bf8 bb = *(bf8*)&Wt[(nt * 16 + col) * 136 + kc * 32 + quad * 8];
            acc[nt] = MFMA(a, bb, acc[nt]);
        }
    }
#pragma unroll
    for (int nt = 0; nt < 8; ++nt)
#pragma unroll
        for (int r = 0; r < 4; ++r) {
            int t = tt + w * 16 + quad * 4 + r, n = nt * 16 + col;
            m2b[(long)t * 128 + n] = f2b(acc[nt][r] + b2f(ctb[(long)t * 128 + n]));
        }
}

// ---------------- K10: out = m2 @ W_out (MFMA), scatter --------------------
__global__ __launch_bounds__(256) void k_out(
        const u16* __restrict__ m2b, const float* __restrict__ Wo,
        float* __restrict__ out) {
    int tt = blockIdx.x * 64, tid = threadIdx.x;
    __shared__ u16 As[64 * 136], Wt[64 * 136];
    for (int idx = tid; idx < 8192; idx += 256) {
        int k = idx >> 6, o = idx & 63;
        Wt[o * 136 + k] = f2b(Wo[idx]);
    }
    for (int idx = tid; idx < 2048; idx += 256) {
        int row = idx >> 5, kg = (idx & 31) * 4;
        *(ushort4*)&As[row * 136 + kg] = *(const ushort4*)(m2b + (long)(tt + row) * 128 + kg);
    }
    __syncthreads();
    int w = tid >> 6, l = tid & 63, quad = l >> 4, col = l & 15;
    f4 z = {0.f, 0.f, 0.f, 0.f};
    f4 acc[4]; for (int i = 0; i < 4; ++i) acc[i] = z;
#pragma unroll
    for (int kc = 0; kc < 4; ++kc) {
        bf8 a = *(bf8*)&As[(w * 16 + col) * 136 + kc * 32 + quad * 8];
#pragma unroll
        for (int nt = 0; nt < 4; ++nt) {
            bf8 bb = *(bf8*)&Wt[(nt * 16 + col) * 136 + kc * 32 + quad * 8];
            acc[nt] = MFMA(a, bb, acc[nt]);
        }
    }
    int t0 = tt + w * 16 + quad * 4;
    int bn = t0 >> 10, hw = t0 & 1023;
    int b = bn / 25, uv = bn - b * 25;
#pragma unroll
    for (int nt = 0; nt < 4; ++nt) {
        int o = nt * 16 + col;
        float4 pk = {acc[nt][0], acc[nt][1], acc[nt][2], acc[nt][3]};
        *(float4*)(out + ((long)((b * 64 + o) * 25 + uv)) * 1024 + hw) = pk;
    }
}

// ---------------- launch ---------------------------------------------------
extern "C" void kernel_launch(void* const* d_in, const int* in_sizes, int n_in,
                              void* d_out, int out_size, void* d_ws, size_t ws_size,
                              hipStream_t stream) {
    const float* x_lf = (const float*)d_in[0];
    const float* x_hf = (const float*)d_in[1];
    const float* W_in = (const float*)d_in[2];
    const float* W_kv = (const float*)d_in[3];
    const float* ln_g = (const float*)d_in[4];
    const float* ln_b = (const float*)d_in[5];
    const float* W_m1 = (const float*)d_in[6];
    const float* W_m2 = (const float*)d_in[7];
    const float* W_ot = (const float*)d_in[8];
    float* out = (float*)d_out;

    float* ws = (float*)d_ws;
    u16*   qb    = (u16*)ws;                          // 13.1M bf16
    u16*   h1b   = qb;                                // reuse after attention
    u16*   kvb   = (u16*)(ws + 6553600);              // 13.1M bf16
    u16*   m2b   = kvb;                               // reuse after ogemms+mlp1... (mlp2 writes after kvb dead)
    u16*   catb  = (u16*)(ws + 13107200);             // 13.1M bf16
    u16*   ctb   = (u16*)(ws + 19660800);             // 13.1M bf16
    u16*   Sb    = (u16*)(ws + 26214400);             // 4.19M bf16 (att0 scores)
    u16*   Pb    = (u16*)(ws + 28311552);             // 4.19M bf16 (att0 probs)
    u16*   Pb12  = (u16*)(ws + 30408704);             // 102400 bf16 (att1/2 probs)
    float* Spart = ws + 30459904;                     // <= 1.23M fp32
    float* nq    = ws + 31688704;
    float* nk    = nq + 4096;
    float* mu    = nk + 4096;
    float* rstd  = mu + 102400;

    // 1. token GEMMs -> bf16 q/kv
    k_tokens<<<dim3(400, 4, 2), 256, 0, stream>>>(x_hf, x_lf, W_in, W_kv, qb, kvb);

    // 2. three attentions
    const int Ms[3]  = {1024, 160, 160};
    const int KCs[3] = {25, 160, 320};
    for (int att = 0; att < 3; ++att) {
        int M = Ms[att], KC = KCs[att];
        k_norms2<<<dim3(M, 4, 2), 256, 0, stream>>>(qb, kvb, nq, nk, att, M, KC);
        if (att == 0) {
            k_sgemm0<<<dim3(16, 16, 4), 256, 0, stream>>>(qb, kvb, nq, nk, Sb);
            k_softmax0<<<dim3(M, 4), 256, 0, stream>>>(Sb, Pb, M);
            k_ogemm0<<<dim3(16, 25, 4), 256, 0, stream>>>(Pb, kvb, catb);
        } else {
            int nsplit = KC / 16;                     // att1: 10, att2: 20
            k_sgemm_split<<<dim3(15, nsplit, 4), 256, 0, stream>>>(qb, kvb, Spart, att, nsplit);
            k_softmax12<<<dim3(M, 4), 256, 0, stream>>>(Spart, nq, nk, Pb12, M, nsplit);
            k_ogemm12m<<<dim3(5, KC, 4), 256, 0, stream>>>(Pb12, kvb, catb, att, KC);
        }
    }

    // 3. transpose to token-major (bf16)
    k_transpose<<<dim3(16, 4, 100), 256, 0, stream>>>(catb, ctb);

    // 4. LN + MLP + out projection
    k_lnstats<<<dim3(25600), 256, 0, stream>>>(ctb, mu, rstd);
    k_mlp1<<<dim3(1600), 256, 0, stream>>>(ctb, mu, rstd, ln_g, ln_b, W_m1, h1b);
    k_mlp2<<<dim3(1600), 256, 0, stream>>>(h1b, ctb, W_m2, m2b);
    k_out <<<dim3(1600), 256, 0, stream>>>(m2b, W_ot, out);
}